// Round 14
// baseline (520.259 us; speedup 1.0000x reference)
//
#include <hip/hip_runtime.h>

#define H_ 4
#define O_ 32
#define HO 128
#define M_ 128
#define M2 256
#define D_ 16
#define B_ 1024
#define JIT 1e-4f

typedef unsigned short ushort_t;
typedef __bf16 v8bf __attribute__((ext_vector_type(8)));
typedef float v16f __attribute__((ext_vector_type(16)));
typedef unsigned short v8us __attribute__((ext_vector_type(8)));
typedef unsigned short v4us __attribute__((ext_vector_type(4)));

__device__ inline void splitbf(float v, ushort_t& hb, ushort_t& lb) {
    unsigned int u = __float_as_uint(v);
    hb = (ushort_t)(u >> 16);
    float hf = __uint_as_float((unsigned int)hb << 16);
    float r = v - hf;
    lb = (ushort_t)(__float_as_uint(r) >> 16);
}
__device__ inline float bf2f(ushort_t u) { return __uint_as_float((unsigned int)u << 16); }

__device__ __forceinline__ float rdlane(float v, int l) {
    return __int_as_float(__builtin_amdgcn_readlane(__float_as_int(v), l));
}

// aligned packed-triangle row offset: each row start rounded to 4 floats (16B)
__device__ __forceinline__ int ro_(int i) {
    int M = i >> 2, k = i & 3;
    return 4 * (M + 1) * (2 * M + k);
}

// ---------------------------------------------------------------------------
// merged preprocessing + kuu2 (kuu2 split into 2 half-blocks per pair)
// kuu2 loop in log2 domain; float4 z loads
__global__ __launch_bounds__(256) void k_prekuu2(const float* __restrict__ theta,
                                                 const float* __restrict__ x,
                                                 const float* __restrict__ z,
                                                 const float* __restrict__ z_old,
                                                 float* __restrict__ SF2,
                                                 float* __restrict__ XS, float* __restrict__ XN,
                                                 float* __restrict__ ZS, float* __restrict__ ZN,
                                                 float* __restrict__ K2) {
    int bb = blockIdx.x, t = threadIdx.x;
    __shared__ float zs[M2][D_];
    __shared__ float zn[M2];
    __shared__ float ls[D_];
    if (bb == 272) {
        if (t < H_) SF2[t] = __expf(theta[t * (D_ + 1)]);
        return;
    }
    if (bb >= 256) {
        int j = (bb - 256) * 256 + t;
        int h = j >> 10, b = j & 1023;
        if (t < D_) ls[t] = __expf(-theta[h * (D_ + 1) + 1 + t]);
        __syncthreads();
        float s = 0.f;
#pragma unroll
        for (int d = 0; d < D_; d++) {
            float v = x[b * D_ + d] * ls[d];
            XS[(long)j * D_ + d] = v;
            s += v * v;
        }
        XN[j] = s;
        return;
    }
    int pair = bb >> 1, half = bb & 1;
    int h = pair >> 5, o = pair & 31, i = t;
    if (t < D_) ls[t] = __expf(-theta[h * (D_ + 1) + 1 + t]);
    __syncthreads();
    const float* src = (i < M_) ? (z_old + ((long)o * M_ + i) * D_)
                                : (z + ((long)o * M_ + (i - M_)) * D_);
    const float4* s4 = (const float4*)src;
    float s = 0.f;
#pragma unroll
    for (int d4 = 0; d4 < 4; d4++) {
        float4 vv = s4[d4];
        vv.x *= ls[d4 * 4 + 0];
        vv.y *= ls[d4 * 4 + 1];
        vv.z *= ls[d4 * 4 + 2];
        vv.w *= ls[d4 * 4 + 3];
        *(float4*)&zs[i][d4 * 4] = vv;
        if (half == 0) *(float4*)&ZS[((long)pair * M2 + i) * D_ + d4 * 4] = vv;
        s += vv.x * vv.x + vv.y * vv.y + vv.z * vv.z + vv.w * vv.w;
    }
    zn[i] = s;
    if (half == 0) ZN[pair * M2 + i] = s;
    __syncthreads();
    const float LOG2E = 1.4426950408889634f;
    const float NHL = -0.5f * 1.4426950408889634f;
    float lsf2 = theta[h * (D_ + 1)] * LOG2E;
    float my[D_];
#pragma unroll
    for (int d = 0; d < D_; d++) my[d] = zs[i][d];
    float bx = NHL * zn[i];
    int q0 = half * 128;
    for (int q = q0; q < q0 + 128; q++) {
        float dot = 0.f;
#pragma unroll
        for (int d = 0; d < D_; d++) dot += zs[q][d] * my[d];
        float pre = fmaf(zn[q], NHL, fmaf(dot, LOG2E, bx));
        float wexp = fminf(pre, 0.f) + lsf2;
        float v;
        asm("v_exp_f32 %0, %1" : "=v"(v) : "v"(wexp));
        if (q == i) v += JIT;
        K2[(long)pair * M2 * M2 + (long)q * M2 + i] = v;
    }
}

// ---------------------------------------------------------------------------
// chol(128)+trinv body, 256 threads (spill-free), LDS ops vectorized.
// software pipeline: P3 split into P3a (next-diag tiles, tp<36) and P3b;
// wave 0 runs P1(kb+1) concurrently with waves 1-3 running P3b(kb).
#define AP_SZ 8448
#define LV_SZ 16896
#define WS_SZ 4608
#define TM_SZ 3456
#define SH_TOTAL (AP_SZ + LV_SZ + WS_SZ + TM_SZ + 128)

// wave-0 register cholesky of 32x32 diag block at column offset c0
__device__ __forceinline__ void chol_diag32(float* __restrict__ Ap, float* __restrict__ rdia,
                                            int c0, int lane, int r) {
    float a[32];
    int gr = c0 + r;
    int base = ro_(gr) + c0;
#pragma unroll
    for (int j = 0; j < 32; j++) a[j] = Ap[base + j];  // j>r: garbage, unused
#pragma unroll
    for (int k = 0; k < 32; k++) {
        float dk = rdlane(a[k], k);
        float rs = rsqrtf(dk);
        rs = rs * (1.5f - 0.5f * dk * rs * rs);  // Newton refine
        a[k] *= rs;
        if (lane == k) rdia[c0 + k] = rs;
#pragma unroll
        for (int j = k + 1; j < 32; j++) {
            float ljk = rdlane(a[k], j);
            a[j] = fmaf(-a[k], ljk, a[j]);
        }
    }
    if (lane < 32) {
#pragma unroll
        for (int j = 0; j < 32; j++)
            if (j <= r) Ap[base + j] = a[j];
    }
}

// one 4x4 trailing-syrk tile (triangular tile index tp, panel col c0)
__device__ __forceinline__ void syrk_tile(float* __restrict__ Ap, int c0, int tp) {
    int bi = (int)((sqrtf(8.f * tp + 1.f) - 1.f) * 0.5f);
    while ((bi + 1) * (bi + 2) / 2 <= tp) bi++;
    while (bi * (bi + 1) / 2 > tp) bi--;
    int bj = tp - bi * (bi + 1) / 2;
    int i0 = c0 + 32 + bi * 4, j0 = c0 + 32 + bj * 4;
    int ra[4], rb[4];
#pragma unroll
    for (int q = 0; q < 4; q++) {
        ra[q] = ro_(i0 + q) + c0;
        rb[q] = ro_(j0 + q) + c0;
    }
    float acc[4][4] = {};
#pragma unroll
    for (int k4 = 0; k4 < 8; k4++) {
        float4 av[4], bv[4];
#pragma unroll
        for (int q = 0; q < 4; q++) {
            av[q] = *(const float4*)&Ap[ra[q] + k4 * 4];
            bv[q] = *(const float4*)&Ap[rb[q] + k4 * 4];
        }
#pragma unroll
        for (int q = 0; q < 4; q++)
#pragma unroll
            for (int rr = 0; rr < 4; rr++)
                acc[q][rr] += av[q].x * bv[rr].x + av[q].y * bv[rr].y +
                              av[q].z * bv[rr].z + av[q].w * bv[rr].w;
    }
#pragma unroll
    for (int q = 0; q < 4; q++)
#pragma unroll
        for (int rr = 0; rr < 4; rr++) {
            int gi = i0 + q, gj = j0 + rr;
            if (gj <= gi) Ap[ro_(gi) + gj] -= acc[q][rr];
        }
}

__device__ __forceinline__ void choltri_body(const float* __restrict__ S, int ldsrc,
                                             float* __restrict__ Li, long b1, int t,
                                             float* __restrict__ Ap, float* __restrict__ Lv,
                                             float* __restrict__ Ws4, float* __restrict__ Tm,
                                             float* __restrict__ rdia) {
    // coalesced float4 load into aligned-row packed triangle
#pragma unroll
    for (int u = 0; u < 16; u++) {
        int idx = u * 256 + t;
        int i = idx >> 5, jc = (idx & 31) * 4;
        float4 v = *(const float4*)(S + (long)i * ldsrc + jc);
        int tb = ro_(i) + jc;
        if (jc + 3 <= i) {
            *(float4*)&Ap[tb] = v;
        } else if (jc <= i) {
            Ap[tb] = v.x;
            if (jc + 1 <= i) Ap[tb + 1] = v.y;
            if (jc + 2 <= i) Ap[tb + 2] = v.z;
        }
    }
    __syncthreads();

    int lane = t & 63;
    int wav = t >> 6;
    int r = lane & 31;

    // P1(0): diag block 0 is raw
    if (wav == 0) chol_diag32(Ap, rdia, 0, lane, r);
    __syncthreads();

    for (int kb = 0; kb < 3; kb++) {
        int c0 = kb * 32;
        int R = 96 - c0;  // 96, 64, 32
        // P2: parallel-row forward substitution (broadcast LDS reads)
        if (t < R) {
            int gi = c0 + 32 + t;
            int pb = ro_(gi) + c0;
            float xr[32];
#pragma unroll
            for (int j = 0; j < 32; j++) xr[j] = Ap[pb + j];
#pragma unroll
            for (int q = 0; q < 32; q++) {
                float xq = xr[q] * rdia[c0 + q];
                xr[q] = xq;
#pragma unroll
                for (int j = q + 1; j < 32; j++)
                    xr[j] = fmaf(-xq, Ap[ro_(c0 + j) + c0 + q], xr[j]);
            }
#pragma unroll
            for (int j = 0; j < 32; j++) Ap[pb + j] = xr[j];
        }
        __syncthreads();
        int nb = R >> 2;
        int ntile = nb * (nb + 1) / 2;
        // P3a: next-diag tiles (tp < 36 — rows/cols [c0+32, c0+64))
        if (t < 36) syrk_tile(Ap, c0, t);
        __syncthreads();
        // overlap: wave0 factors next diag while waves 1-3 finish trailing syrk.
        if (wav == 0) {
            chol_diag32(Ap, rdia, c0 + 32, lane, r);
        } else {
            for (int tp = 36 + (t - 64); tp < ntile; tp += 192) syrk_tile(Ap, c0, tp);
        }
        __syncthreads();
    }

    // parallel trinv: wave w inverts diag block w (lanes 32-63 mirror lanes 0-31)
    {
        int pb = wav;
        int c0 = pb * 32;
        float a[32];
        int gr = c0 + r;
        int base = ro_(gr) + c0;
#pragma unroll
        for (int j = 0; j < 32; j++) a[j] = Ap[base + j];
        float wr[32];
#pragma unroll
        for (int i = 0; i < 32; i++) {
            float rdi = rdia[c0 + i];
            float acc = 0.f;
#pragma unroll
            for (int j = 0; j < i; j++) {
                float lij = rdlane(a[j], i);
                acc = fmaf(lij, wr[j], acc);
            }
            wr[i] = (i == r) ? rdi : -acc * rdi;
        }
        if (lane < 32) {
            float* Wp = Ws4 + pb * 1152;
#pragma unroll
            for (int i = 0; i < 32; i++) Wp[i * 36 + r] = wr[i];
        }
    }
    __syncthreads();

    // assemble Linv in LDS (float4): diag blocks = W_i, rest 0
    for (int e = t; e < 4096; e += 256) {
        int i = e >> 5, j = (e & 31) * 4;
        int bi = i >> 5, bj = j >> 5;
        float4 v = make_float4(0.f, 0.f, 0.f, 0.f);
        if (bi == bj) v = *(const float4*)&Ws4[bi * 1152 + (i & 31) * 36 + (j & 31)];
        *(float4*)&Lv[i * 132 + j] = v;
    }
    __syncthreads();
    // block-diagonal sweep (float4): Linv[ib][b] = -W_ib * sum_k L[ib][k] Linv[k][b]
    for (int d = 1; d < 4; d++) {
        int nblk = 4 - d;
        int ne = nblk * 256;
        for (int p = t; p < ne; p += 256) {
            int b = p >> 8, rc = p & 255;
            int rr = rc >> 3, c4 = (rc & 7) * 4;
            int ib = b + d;
            int abase = ro_(ib * 32 + rr);
            float4 acc = make_float4(0.f, 0.f, 0.f, 0.f);
            for (int k = b; k < ib; k++) {
                const float* Arow = Ap + abase + k * 32;
                const float* L0 = Lv + (k * 32) * 132 + b * 32 + c4;
#pragma unroll
                for (int q4 = 0; q4 < 8; q4++) {
                    float4 ar = *(const float4*)(Arow + q4 * 4);
                    const float* Lq = L0 + (q4 * 4) * 132;
                    float4 l0 = *(const float4*)(Lq);
                    float4 l1 = *(const float4*)(Lq + 132);
                    float4 l2 = *(const float4*)(Lq + 264);
                    float4 l3 = *(const float4*)(Lq + 396);
                    acc.x += ar.x * l0.x + ar.y * l1.x + ar.z * l2.x + ar.w * l3.x;
                    acc.y += ar.x * l0.y + ar.y * l1.y + ar.z * l2.y + ar.w * l3.y;
                    acc.z += ar.x * l0.z + ar.y * l1.z + ar.z * l2.z + ar.w * l3.z;
                    acc.w += ar.x * l0.w + ar.y * l1.w + ar.z * l2.w + ar.w * l3.w;
                }
            }
            *(float4*)(Tm + b * 1152 + rr * 36 + c4) = acc;
        }
        __syncthreads();
        for (int p = t; p < ne; p += 256) {
            int b = p >> 8, rc = p & 255;
            int rr = rc >> 3, c4 = (rc & 7) * 4;
            int ib = b + d;
            const float* Wp = Ws4 + ib * 1152 + rr * 36;
            const float* T0 = Tm + b * 1152 + c4;
            float4 acc = make_float4(0.f, 0.f, 0.f, 0.f);
#pragma unroll
            for (int q4 = 0; q4 < 8; q4++) {
                float4 w4 = *(const float4*)(Wp + q4 * 4);
                const float* Tq = T0 + (q4 * 4) * 36;
                float4 t0 = *(const float4*)(Tq);
                float4 t1 = *(const float4*)(Tq + 36);
                float4 t2 = *(const float4*)(Tq + 72);
                float4 t3 = *(const float4*)(Tq + 108);
                acc.x += w4.x * t0.x + w4.y * t1.x + w4.z * t2.x + w4.w * t3.x;
                acc.y += w4.x * t0.y + w4.y * t1.y + w4.z * t2.y + w4.w * t3.y;
                acc.z += w4.x * t0.z + w4.y * t1.z + w4.z * t2.z + w4.w * t3.z;
                acc.w += w4.x * t0.w + w4.y * t1.w + w4.z * t2.w + w4.w * t3.w;
            }
            *(float4*)(Lv + (ib * 32 + rr) * 132 + b * 32 + c4) =
                make_float4(-acc.x, -acc.y, -acc.z, -acc.w);
        }
        __syncthreads();
    }
    // coalesced float4 writeback
#pragma unroll
    for (int u = 0; u < 16; u++) {
        int idx = u * 256 + t;
        int i = idx >> 5, jc = (idx & 31) * 4;
        *(float4*)(Li + b1 + (long)i * 128 + jc) = *(const float4*)(Lv + i * 132 + jc);
    }
}

// chol TL + co-scheduled WcT part A (UT BR quadrant, zeros, L_old part)
__global__ __launch_bounds__(256) void k_choltri_tl(const float* __restrict__ src,
                                                    float* __restrict__ Li,
                                                    const float* __restrict__ L_old,
                                                    const float* __restrict__ vec,
                                                    ushort_t* __restrict__ WTh,
                                                    ushort_t* __restrict__ WTl) {
    int bb = blockIdx.x, t = threadIdx.x;
    __shared__ __align__(16) float SH[SH_TOTAL];
    if (bb < 128) {
        choltri_body(src + (long)bb * ((long)M2 * M2), M2, Li, (long)bb * 16384, t,
                     SH, SH + AP_SZ, SH + AP_SZ + LV_SZ, SH + AP_SZ + LV_SZ + WS_SZ,
                     SH + AP_SZ + LV_SZ + WS_SZ + TM_SZ);
        return;
    }
    // co-path: WcT part A for pair bb-128
    int pair = bb - 128, o = pair & 31;
    long b2 = (long)pair * 65536;
    float* vs = SH;  // alias (8256 floats fits in AP region)
    float(*tile)[33] = (float(*)[33])(SH + AP_SZ);
    for (int e = t; e < M_ * (M_ + 1) / 2; e += 256) vs[e] = vec[(long)o * (M_ * (M_ + 1) / 2) + e];
    __syncthreads();
    for (int e = t; e < 16384; e += 256) {
        int n = e >> 7, k = e & 127;
        float v = (k >= n) ? vs[k * (k + 1) / 2 + n] : 0.f;
        ushort_t hb, lb;
        splitbf(v, hb, lb);
        long a = b2 + (long)(128 + n) * 256 + 128 + k;
        WTh[a] = hb;
        WTl[a] = lb;
    }
    for (int e = t; e < 16384; e += 256) {
        int n = e >> 7, k = e & 127;
        long a = b2 + (long)(128 + n) * 256 + k;
        WTh[a] = 0;
        WTl[a] = 0;
    }
    const float* sp = L_old + (long)o * 16384;
    int tx = t & 31, ty = t >> 5;
    for (int bi = 0; bi < 4; bi++)
        for (int bj = 0; bj < 4; bj++) {
            __syncthreads();
            for (int r = ty; r < 32; r += 8)
                tile[r][tx] = sp[(long)(bi * 32 + r) * 128 + bj * 32 + tx];
            __syncthreads();
            for (int r = ty; r < 32; r += 8) {
                ushort_t hb, lb;
                splitbf(tile[tx][r], hb, lb);
                long a = b2 + (long)(bj * 32 + r) * 256 + bi * 32 + tx;
                WTh[a] = hb;
                WTl[a] = lb;
            }
        }
}

// chol BR + co-scheduled: T1 = A1^T Linv1 (blocks 128-255), LINVT zeros+Linv1 part
// (256-383), WcT BLW part (384-511)
__global__ __launch_bounds__(256) void k_choltri_br(const float* __restrict__ src,
                                                    float* __restrict__ Li,
                                                    const float* __restrict__ A1,
                                                    const float* __restrict__ Linv1,
                                                    float* __restrict__ T1g,
                                                    const float* __restrict__ BLW,
                                                    ushort_t* __restrict__ LTh,
                                                    ushort_t* __restrict__ LTl,
                                                    ushort_t* __restrict__ WTh,
                                                    ushort_t* __restrict__ WTl) {
    int bb = blockIdx.x, t = threadIdx.x;
    __shared__ __align__(16) float SH[SH_TOTAL];
    if (bb < 128) {
        choltri_body(src + (long)bb * ((long)M2 * M2), M2, Li, (long)bb * 16384, t,
                     SH, SH + AP_SZ, SH + AP_SZ + LV_SZ, SH + AP_SZ + LV_SZ + WS_SZ,
                     SH + AP_SZ + LV_SZ + WS_SZ + TM_SZ);
        return;
    }
    if (bb < 256) {
        // T1 = A1^T @ Linv1 -> T1g (per-pair stride 65536)
        int pair = bb - 128;
        long b1 = (long)pair * 16384;
        float(*As)[132] = (float(*)[132])(SH + AP_SZ);
        float(*Bs)[132] = ((float(*)[132])(SH + AP_SZ)) + 16;
        const float* Apt = A1 + b1;
        const float* Bpt = Linv1 + b1;
        float* Cp = T1g + (long)pair * 65536;
        int tx = t & 15, ty = t >> 4;
        float acc[8][8] = {};
        for (int kt = 0; kt < M_; kt += 16) {
#pragma unroll
            for (int q = 0; q < 8; q++) {
                int e = q * 256 + t;
                int kk = e >> 7, m = e & 127;
                As[kk][m] = Apt[(long)(kt + kk) * 128 + m];
                Bs[kk][m] = Bpt[(long)(kt + kk) * 128 + m];
            }
            __syncthreads();
#pragma unroll
            for (int kk = 0; kk < 16; kk++) {
                float a[8], b[8];
#pragma unroll
                for (int q = 0; q < 8; q++) { a[q] = As[kk][ty + 16 * q]; b[q] = Bs[kk][tx + 16 * q]; }
#pragma unroll
                for (int q = 0; q < 8; q++)
#pragma unroll
                    for (int r = 0; r < 8; r++) acc[q][r] += a[q] * b[r];
            }
            __syncthreads();
        }
#pragma unroll
        for (int q = 0; q < 8; q++)
#pragma unroll
            for (int r = 0; r < 8; r++)
                Cp[(long)(ty + 16 * q) * 128 + tx + 16 * r] = acc[q][r];
        return;
    }
    if (bb < 384) {
        // LINVT zeros (rows 128+, cols<128) + Linv1 part
        int pair = bb - 256;
        long b2 = (long)pair * 65536, b1 = (long)pair * 16384;
        float(*tile)[33] = (float(*)[33])(SH + AP_SZ);
        for (int e = t; e < 16384; e += 256) {
            int n = e >> 7, k = e & 127;
            long a = b2 + (long)(128 + n) * 256 + k;
            LTh[a] = 0;
            LTl[a] = 0;
        }
        const float* sp = Linv1 + b1;
        int tx = t & 31, ty = t >> 5;
        for (int bi = 0; bi < 4; bi++)
            for (int bj = 0; bj < 4; bj++) {
                __syncthreads();
                for (int r = ty; r < 32; r += 8)
                    tile[r][tx] = sp[(long)(bi * 32 + r) * 128 + bj * 32 + tx];
                __syncthreads();
                for (int r = ty; r < 32; r += 8) {
                    ushort_t hb, lb;
                    splitbf(tile[tx][r], hb, lb);
                    long a = b2 + (long)(bj * 32 + r) * 256 + bi * 32 + tx;
                    LTh[a] = hb;
                    LTl[a] = lb;
                }
            }
        return;
    }
    {
        // WcT part B: BLW transposed into cols 128.. rows <128
        int pair = bb - 384;
        long b2 = (long)pair * 65536, b1 = (long)pair * 16384;
        float(*tile)[33] = (float(*)[33])(SH + AP_SZ);
        const float* sp = BLW + b1;
        int tx = t & 31, ty = t >> 5;
        for (int bi = 0; bi < 4; bi++)
            for (int bj = 0; bj < 4; bj++) {
                __syncthreads();
                for (int r = ty; r < 32; r += 8)
                    tile[r][tx] = sp[(long)(bi * 32 + r) * 128 + bj * 32 + tx];
                __syncthreads();
                for (int r = ty; r < 32; r += 8) {
                    ushort_t hb, lb;
                    splitbf(tile[tx][r], hb, lb);
                    long a = b2 + (long)(bj * 32 + r) * 256 + 128 + bi * 32 + tx;
                    WTh[a] = hb;
                    WTl[a] = lb;
                }
            }
    }
}

// merged A1/A3: y=0: A1 = Linv1 @ kuf(KUU2 TR); y=1: A3 = Linv1 @ L_old
__global__ __launch_bounds__(256) void k_a1a3(const float* __restrict__ Linv1,
                                              const float* __restrict__ KUU2,
                                              const float* __restrict__ L_old,
                                              float* __restrict__ A1, float* __restrict__ A3) {
    int pair = blockIdx.x, y = blockIdx.y, o = pair & 31;
    const float* Ap = Linv1 + (long)pair * 16384;
    const float* Bp = y ? (L_old + (long)o * 16384) : (KUU2 + (long)pair * 65536 + 128);
    int ldb = y ? 128 : 256;
    float* Cp = (y ? A3 : A1) + (long)pair * 16384;
    int t = threadIdx.x, tx = t & 15, ty = t >> 4;
    __shared__ float As[16][132], Bs[16][132];
    float acc[8][8] = {};
    for (int kt = 0; kt < M_; kt += 16) {
#pragma unroll
        for (int q = 0; q < 8; q++) {
            int e = q * 256 + t;
            int m = e >> 4, kk = e & 15;
            As[kk][m] = Ap[(long)m * 128 + kt + kk];
            int kk2 = e >> 7, n = e & 127;
            Bs[kk2][n] = Bp[(long)(kt + kk2) * ldb + n];
        }
        __syncthreads();
#pragma unroll
        for (int kk = 0; kk < 16; kk++) {
            float a[8], b[8];
#pragma unroll
            for (int q = 0; q < 8; q++) { a[q] = As[kk][ty + 16 * q]; b[q] = Bs[kk][tx + 16 * q]; }
#pragma unroll
            for (int q = 0; q < 8; q++)
#pragma unroll
                for (int r = 0; r < 8; r++) acc[q][r] += a[q] * b[r];
        }
        __syncthreads();
    }
#pragma unroll
    for (int q = 0; q < 8; q++)
#pragma unroll
        for (int r = 0; r < 8; r++)
            Cp[(long)(ty + 16 * q) * 128 + tx + 16 * r] = acc[q][r];
}

// merged: y=0: BLW = A1^T A3; y=1: KUU2_BR -= A1^T A1; y=2: m_joint + CV zero
__global__ __launch_bounds__(256) void k_blwschur(const float* __restrict__ A1,
                                                  const float* __restrict__ A3,
                                                  float* __restrict__ BLW,
                                                  float* __restrict__ KUU2,
                                                  const float* __restrict__ Linv1,
                                                  const float* __restrict__ m_old,
                                                  const float* __restrict__ u_mean,
                                                  float* __restrict__ MJ,
                                                  float* __restrict__ CV) {
    int pair = blockIdx.x, y = blockIdx.y, o = pair & 31;
    int t = threadIdx.x;
    if (y == 2) {
        CV[pair * 256 + t] = 0.f;
        __shared__ float mo[128], a2[128];
        if (t < 128) mo[t] = m_old[o * 128 + t];
        __syncthreads();
        if (t < 128) {
            const float* Lr = Linv1 + (long)pair * 16384 + (long)t * 128;
            float acc = 0.f;
            for (int j = 0; j <= t; j++) acc += Lr[j] * mo[j];
            a2[t] = acc;
        }
        __syncthreads();
        if (t < 128) {
            float m = 0.f;
            for (int i = 0; i < 128; i++) m += A1[(long)pair * 16384 + (long)i * 128 + t] * a2[i];
            MJ[pair * 256 + t] = mo[t];
            MJ[pair * 256 + 128 + t] = m + u_mean[o * 128 + t];
        }
        return;
    }
    const float* Ap = A1 + (long)pair * 16384;
    const float* Bp = (y ? A1 : A3) + (long)pair * 16384;
    float* Cp;
    int ldc;
    if (y) { Cp = KUU2 + (long)pair * 65536 + 128L * 256 + 128; ldc = 256; }
    else   { Cp = BLW + (long)pair * 16384; ldc = 128; }
    int tx = t & 15, ty = t >> 4;
    __shared__ float As[16][132], Bs[16][132];
    float acc[8][8] = {};
    for (int kt = 0; kt < M_; kt += 16) {
#pragma unroll
        for (int q = 0; q < 8; q++) {
            int e = q * 256 + t;
            int kk = e >> 7, m = e & 127;
            As[kk][m] = Ap[(long)(kt + kk) * 128 + m];
            Bs[kk][m] = Bp[(long)(kt + kk) * 128 + m];
        }
        __syncthreads();
#pragma unroll
        for (int kk = 0; kk < 16; kk++) {
            float a[8], b[8];
#pragma unroll
            for (int q = 0; q < 8; q++) { a[q] = As[kk][ty + 16 * q]; b[q] = Bs[kk][tx + 16 * q]; }
#pragma unroll
            for (int q = 0; q < 8; q++)
#pragma unroll
                for (int r = 0; r < 8; r++) acc[q][r] += a[q] * b[r];
        }
        __syncthreads();
    }
#pragma unroll
    for (int q = 0; q < 8; q++)
#pragma unroll
        for (int r = 0; r < 8; r++) {
            long idx = (long)(ty + 16 * q) * ldc + tx + 16 * r;
            if (y) Cp[idx] -= acc[q][r];
            else Cp[idx] = acc[q][r];
        }
}

// BLi = -Linv2 @ T1g; write LINVT BLi-part planes (transposed) + Linv2 part
// SPLIT over y in {0,1}: each block handles 64 output rows (full grid coverage)
__global__ __launch_bounds__(256) void k_blicalc2(const float* __restrict__ Linv2,
                                                  const float* __restrict__ T1g,
                                                  ushort_t* __restrict__ LTh,
                                                  ushort_t* __restrict__ LTl) {
    int pair = blockIdx.x, y = blockIdx.y;
    int t = threadIdx.x, tx = t & 15, ty = t >> 4;
    long b1 = (long)pair * 16384, b2 = (long)pair * 65536;
    int m0 = y * 64;
    __shared__ float T1s[64][129];
    __shared__ float As[16][68], Bs[16][132];
    const float* Apt = Linv2 + b1;
    const float* Bpt = T1g + (long)pair * 65536;
    float acc[4][8] = {};
    for (int kt = 0; kt < M_; kt += 16) {
#pragma unroll
        for (int q = 0; q < 4; q++) {
            int e = q * 256 + t;
            int m = e >> 4, kk = e & 15;  // m 0..63
            As[kk][m] = Apt[(long)(m0 + m) * 128 + kt + kk];
        }
#pragma unroll
        for (int q = 0; q < 8; q++) {
            int e = q * 256 + t;
            int kk2 = e >> 7, n = e & 127;
            Bs[kk2][n] = Bpt[(long)(kt + kk2) * 128 + n];
        }
        __syncthreads();
#pragma unroll
        for (int kk = 0; kk < 16; kk++) {
            float a[4], b[8];
#pragma unroll
            for (int q = 0; q < 4; q++) a[q] = As[kk][ty + 16 * q];
#pragma unroll
            for (int r = 0; r < 8; r++) b[r] = Bs[kk][tx + 16 * r];
#pragma unroll
            for (int q = 0; q < 4; q++)
#pragma unroll
                for (int r = 0; r < 8; r++) acc[q][r] += a[q] * b[r];
        }
        __syncthreads();
    }
#pragma unroll
    for (int q = 0; q < 4; q++)
#pragma unroll
        for (int r = 0; r < 8; r++) T1s[ty + 16 * q][tx + 16 * r] = -acc[q][r];
    __syncthreads();
    // LINVT[j][128 + m0 + i2] = BLi[m0+i2][j]
    for (int e = t; e < 8192; e += 256) {
        int j = e >> 6, i2 = e & 63;
        ushort_t hb, lb;
        splitbf(T1s[i2][j], hb, lb);
        long a = b2 + (long)j * 256 + 128 + m0 + i2;
        LTh[a] = hb;
        LTl[a] = lb;
    }
    __syncthreads();
    // load Linv2 rows [m0, m0+64) and write LINVT[128+n][128+m0+k2] = Linv2[m0+k2][n]
    for (int e = t; e < 8192; e += 256) {
        int k2 = e >> 7, j = e & 127;
        T1s[k2][j] = Apt[(long)(m0 + k2) * 128 + j];
    }
    __syncthreads();
    for (int e = t; e < 8192; e += 256) {
        int n = e >> 6, k2 = e & 63;
        ushort_t hb, lb;
        splitbf(T1s[k2][n], hb, lb);
        long a = b2 + (long)(128 + n) * 256 + 128 + m0 + k2;
        LTh[a] = hb;
        LTl[a] = lb;
    }
}

// split-bf16 MFMA batched GEMM: C = alpha*(Ah+Al)(Bh+Bl)^T [+ (DmH+DmL)]
// optional fused matvec: CVat += C @ MJv
#define BSTR 56
template <int TILES3>
__global__ __launch_bounds__(256) void k_bmmx(const ushort_t* __restrict__ Ah,
                                              const ushort_t* __restrict__ Al,
                                              const ushort_t* __restrict__ Bh,
                                              const ushort_t* __restrict__ Bl,
                                              float* __restrict__ Cf,
                                              ushort_t* __restrict__ Chi,
                                              ushort_t* __restrict__ Clo,
                                              const ushort_t* __restrict__ DmH,
                                              const ushort_t* __restrict__ DmL,
                                              int kLoMode, float alpha,
                                              const float* __restrict__ MJv,
                                              float* __restrict__ CVat) {
    int pair = blockIdx.x;
    long base = (long)pair * 65536;
    int I0, J0, mir = 0;
    if (TILES3) {
        int qb = blockIdx.y;
        I0 = (qb == 0) ? 0 : 128;
        J0 = (qb == 2) ? 0 : I0;
        mir = (qb == 2);
    } else {
        I0 = (blockIdx.y >> 1) * 128;
        J0 = (blockIdx.y & 1) * 128;
    }
    int k0 = (kLoMode == 1) ? max(I0, J0) : (kLoMode == 2) ? J0 : 0;
    int t = threadIdx.x;
    int w = t >> 6, lane = t & 63;
    int l31 = lane & 31, lhalf = lane >> 5;
    int wy = w >> 1, wx = w & 1;

    __shared__ __align__(16) ushort_t AsH[128][BSTR], AsL[128][BSTR];
    __shared__ __align__(16) ushort_t BsH[128][BSTR], BsL[128][BSTR];

    v16f acc[2][2];
#pragma unroll
    for (int mt = 0; mt < 2; mt++)
#pragma unroll
        for (int nt = 0; nt < 2; nt++)
#pragma unroll
            for (int r = 0; r < 16; r++) acc[mt][nt][r] = 0.f;

    for (int kt = k0; kt < 256; kt += 32) {
        __syncthreads();
#pragma unroll
        for (int u = 0; u < 2; u++) {
            int idx = u * 256 + t;
            int m = idx >> 2, kc = (idx & 3) * 8;
            long arow = base + (long)(I0 + m) * 256 + kt + kc;
            long brow = base + (long)(J0 + m) * 256 + kt + kc;
            *(v8us*)&AsH[m][kc] = *(const v8us*)(Ah + arow);
            *(v8us*)&AsL[m][kc] = *(const v8us*)(Al + arow);
            *(v8us*)&BsH[m][kc] = *(const v8us*)(Bh + brow);
            *(v8us*)&BsL[m][kc] = *(const v8us*)(Bl + brow);
        }
        __syncthreads();
#pragma unroll
        for (int ks = 0; ks < 2; ks++) {
            int ko = ks * 16 + lhalf * 8;
            v8bf ah[2], al[2], bh[2], bl[2];
#pragma unroll
            for (int mt = 0; mt < 2; mt++) {
                int r = wy * 64 + mt * 32 + l31;
                ah[mt] = *(const v8bf*)&AsH[r][ko];
                al[mt] = *(const v8bf*)&AsL[r][ko];
            }
#pragma unroll
            for (int nt = 0; nt < 2; nt++) {
                int r = wx * 64 + nt * 32 + l31;
                bh[nt] = *(const v8bf*)&BsH[r][ko];
                bl[nt] = *(const v8bf*)&BsL[r][ko];
            }
#pragma unroll
            for (int mt = 0; mt < 2; mt++)
#pragma unroll
                for (int nt = 0; nt < 2; nt++) {
                    acc[mt][nt] = __builtin_amdgcn_mfma_f32_32x32x16_bf16(ah[mt], bh[nt], acc[mt][nt], 0, 0, 0);
                    acc[mt][nt] = __builtin_amdgcn_mfma_f32_32x32x16_bf16(ah[mt], bl[nt], acc[mt][nt], 0, 0, 0);
                    acc[mt][nt] = __builtin_amdgcn_mfma_f32_32x32x16_bf16(al[mt], bh[nt], acc[mt][nt], 0, 0, 0);
                }
        }
    }

    float mjc[2] = {0.f, 0.f};
    float cvmir[2] = {0.f, 0.f};
    if (MJv) {
#pragma unroll
        for (int nt = 0; nt < 2; nt++)
            mjc[nt] = MJv[(long)pair * 256 + J0 + wx * 64 + nt * 32 + l31];
    }
#pragma unroll
    for (int mt = 0; mt < 2; mt++) {
#pragma unroll
        for (int r = 0; r < 16; r++) {
            int row = I0 + wy * 64 + mt * 32 + 8 * (r >> 2) + 4 * lhalf + (r & 3);
            float rowsum = 0.f;
            float mjrow = 0.f;
            if (MJv && mir) mjrow = MJv[(long)pair * 256 + row];
#pragma unroll
            for (int nt = 0; nt < 2; nt++) {
                int col = J0 + wx * 64 + nt * 32 + l31;
                long idx = base + (long)row * 256 + col;
                float v = alpha * acc[mt][nt][r];
                if (DmH) v += bf2f(DmH[idx]) + bf2f(DmL[idx]);
                ushort_t hb, lb;
                splitbf(v, hb, lb);
                if (Cf) Cf[idx] = v;
                if (Chi) { Chi[idx] = hb; Clo[idx] = lb; }
                if (mir) {
                    long idxT = base + (long)col * 256 + row;
                    if (Cf) Cf[idxT] = v;
                    if (Chi) { Chi[idxT] = hb; Clo[idxT] = lb; }
                }
                if (MJv) {
                    rowsum += v * mjc[nt];
                    if (mir) cvmir[nt] += v * mjrow;
                }
            }
            if (MJv) {
#pragma unroll
                for (int m = 1; m < 32; m <<= 1) rowsum += __shfl_xor(rowsum, m, 64);
                if (l31 == 0) atomicAdd(&CVat[(long)pair * 256 + row], rowsum);
            }
        }
    }
    if (MJv && mir) {
#pragma unroll
        for (int nt = 0; nt < 2; nt++)
            atomicAdd(&CVat[(long)pair * 256 + J0 + wx * 64 + nt * 32 + l31], cvmir[nt]);
    }
}

#define KTP 264
// K build: per (bt-pair, pair): stage Z panel ONCE, process TWO 64-b tiles.
// Z panel / zn / cv staged in LDS (broadcast ds reads replace global loads)
__global__ __launch_bounds__(256) void k_kbuild(const float* __restrict__ ZS, const float* __restrict__ ZN,
                                                const float* __restrict__ XS, const float* __restrict__ XN,
                                                const float* __restrict__ SF2, const float* __restrict__ CV,
                                                ushort_t* __restrict__ Kg, float* __restrict__ out) {
    int bt0 = blockIdx.x * 2;
    int pair = blockIdx.y;
    int h = pair >> 5;
    int t = threadIdx.x;
    int w = t >> 6;
    int b = t & 63;

    __shared__ __align__(16) ushort_t KbT[64][KTP];
    __shared__ float mup[4][64];
    __shared__ __align__(16) float zsL[256 * 16];
    __shared__ float znv[256], cvv[256];

    const float LOG2E = 1.4426950408889634f;
    const float NHL = -0.5f * 1.4426950408889634f;
    float sf2 = SF2[h];
    float lsf2 = __log2f(sf2);

    // stage Z panel (16KB) + zn + cv once for both tiles
    {
        const float4* zsrc = (const float4*)(ZS + (long)pair * 256 * 16);
        float4* zdst = (float4*)zsL;
#pragma unroll
        for (int u = 0; u < 4; u++) zdst[u * 256 + t] = zsrc[u * 256 + t];
        znv[t] = ZN[pair * 256 + t];
        cvv[t] = CV[pair * 256 + t];
    }
    __syncthreads();

    for (int bt2 = 0; bt2 < 2; bt2++) {
        int bt = bt0 + bt2;
        long bg = (long)h * B_ + bt * 64 + b;
        const float4* xrow = (const float4*)(XS + bg * 16);
        float4 x0 = xrow[0], x1 = xrow[1], x2 = xrow[2], x3 = xrow[3];
        float bx = NHL * XN[bg];

        float mupart = 0.f;
#pragma unroll 2
        for (int j8 = 0; j8 < 8; j8++) {
            v8us kb8;
#pragma unroll
            for (int e = 0; e < 8; e++) {
                int j = w * 64 + j8 * 8 + e;
                const float4* zrow = (const float4*)(zsL + j * 16);
                float4 z0 = zrow[0], z1 = zrow[1], z2 = zrow[2], z3 = zrow[3];
                float dot = z0.x * x0.x + z0.y * x0.y + z0.z * x0.z + z0.w * x0.w +
                            z1.x * x1.x + z1.y * x1.y + z1.z * x1.z + z1.w * x1.w +
                            z2.x * x2.x + z2.y * x2.y + z2.z * x2.z + z2.w * x2.w +
                            z3.x * x3.x + z3.y * x3.y + z3.z * x3.z + z3.w * x3.w;
                float pre = fmaf(znv[j], NHL, fmaf(dot, LOG2E, bx));
                float wexp = fminf(pre, 0.f) + lsf2;
                float kv;
                asm("v_exp_f32 %0, %1" : "=v"(kv) : "v"(wexp));
                mupart += cvv[j] * kv;
                unsigned int u = __float_as_uint(kv);
                u += 0x7fffu + ((u >> 16) & 1u);
                kb8[e] = (unsigned short)(u >> 16);
            }
            *(v8us*)&KbT[b][w * 64 + j8 * 8] = kb8;
        }
        mup[w][b] = mupart;
        __syncthreads();
        long kbase = ((long)pair * 1024 + bt * 64) * 256;
#pragma unroll
        for (int e = 0; e < 8; e++) {
            int c = e * 256 + t;
            int bb = c >> 5, cj = (c & 31) * 8;
            *(v8us*)(Kg + kbase + (long)bb * 256 + cj) = *(const v8us*)&KbT[bb][cj];
        }
        if (t < 64) {
            float mu = mup[0][t] + mup[1][t] + mup[2][t] + mup[3][t];
            out[(long)pair * 1024 + bt * 64 + t] = mu;
        }
        __syncthreads();  // KbT/mup reuse safe for next tile
    }
}

// MFMA q kernel, 128-wide b-tiles: 1D grid, pair = idx&127 (XCD L2 locality for G)
#define KT2 264
__global__ __launch_bounds__(256) void k_kb4(const ushort_t* __restrict__ Kg,
                                             const ushort_t* __restrict__ Ghi,
                                             const ushort_t* __restrict__ Glo,
                                             const float* __restrict__ SF2, float* __restrict__ out) {
    int pair = blockIdx.x & 127;
    int bt = blockIdx.x >> 7;
    int h = pair >> 5;
    int t = threadIdx.x;
    int w = t >> 6;
    int lane = t & 63;
    int l31 = lane & 31, lhalf = lane >> 5;

    __shared__ __align__(16) ushort_t KbT[128][KT2];
    __shared__ float qpart[4][128];

    float sf2 = SF2[h];
    long kbase = ((long)pair * 1024 + bt * 128) * 256;
#pragma unroll
    for (int e = 0; e < 16; e++) {
        int c = e * 256 + t;
        int bb = c >> 5, cj = (c & 31) * 8;
        *(v8us*)&KbT[bb][cj] = *(const v8us*)(Kg + kbase + (long)bb * 256 + cj);
    }
    __syncthreads();

    v16f acc[2][4];
#pragma unroll
    for (int mt = 0; mt < 2; mt++)
#pragma unroll
        for (int nt = 0; nt < 4; nt++)
#pragma unroll
            for (int r = 0; r < 16; r++) acc[mt][nt][r] = 0.f;

    const ushort_t* GhiP = Ghi + (long)pair * 65536;
    const ushort_t* GloP = Glo + (long)pair * 65536;
#pragma unroll 2
    for (int k0 = 0; k0 < 256; k0 += 16) {
        v8bf bfr[4];
#pragma unroll
        for (int nt = 0; nt < 4; nt++)
            bfr[nt] = *(const v8bf*)&KbT[nt * 32 + l31][k0 + lhalf * 8];
#pragma unroll
        for (int mt = 0; mt < 2; mt++) {
            int i = w * 64 + mt * 32 + l31;
            v8bf ah = *(const v8bf*)(GhiP + (long)i * 256 + k0 + lhalf * 8);
            v8bf al = *(const v8bf*)(GloP + (long)i * 256 + k0 + lhalf * 8);
#pragma unroll
            for (int nt = 0; nt < 4; nt++) {
                acc[mt][nt] = __builtin_amdgcn_mfma_f32_32x32x16_bf16(ah, bfr[nt], acc[mt][nt], 0, 0, 0);
                acc[mt][nt] = __builtin_amdgcn_mfma_f32_32x32x16_bf16(al, bfr[nt], acc[mt][nt], 0, 0, 0);
            }
        }
    }

    float qp[4] = {0.f, 0.f, 0.f, 0.f};
#pragma unroll
    for (int mt = 0; mt < 2; mt++) {
#pragma unroll
        for (int nt = 0; nt < 4; nt++) {
            int b = nt * 32 + l31;
#pragma unroll
            for (int g = 0; g < 4; g++) {
                int ibase = w * 64 + mt * 32 + 8 * g + 4 * lhalf;
                v4us k4 = *(const v4us*)&KbT[b][ibase];
#pragma unroll
                for (int e = 0; e < 4; e++) {
                    float kv = bf2f(k4[e]);
                    qp[nt] += kv * acc[mt][nt][4 * g + e];
                }
            }
        }
    }
#pragma unroll
    for (int nt = 0; nt < 4; nt++) {
        qp[nt] += __shfl_down(qp[nt], 32, 64);
        if (lhalf == 0) qpart[w][nt * 32 + l31] = qp[nt];
    }
    __syncthreads();

    if (t < 128) {
        float q = qpart[0][t] + qpart[1][t] + qpart[2][t] + qpart[3][t];
        out[(long)H_ * O_ * B_ + (long)pair * 1024 + bt * 128 + t] = sf2 - q;
    }
}

// ---------------------------------------------------------------------------
extern "C" void kernel_launch(void* const* d_in, const int* in_sizes, int n_in,
                              void* d_out, int out_size, void* d_ws, size_t ws_size,
                              hipStream_t stream) {
    const float* x = (const float*)d_in[0];
    const float* z = (const float*)d_in[1];
    const float* u_mean = (const float*)d_in[2];
    const float* u_tril_vec = (const float*)d_in[3];
    const float* m_old = (const float*)d_in[4];
    const float* L_old = (const float*)d_in[5];
    const float* z_old = (const float*)d_in[6];
    const float* theta = (const float*)d_in[7];

    const long BIGSZ = (long)HO * M2 * M2;  // 8388608
    const long MSZ = (long)HO * M_ * M_;    // 2097152

    float* ws = (float*)d_ws;
    long off = 0;
    float* BIG0 = ws + off; off += BIGSZ;  // KUU2 (+T1g in rows<64)
    float* BIG1 = ws + off; off += BIGSZ;  // LINVT h/l -> Y h/l -> Kg (part 1)
    float* BIG2 = ws + off; off += BIGSZ;  // Linv1|A1|Linv2|BLW -> AINV h/l -> Kg (part 2)
    float* BIG3 = ws + off; off += BIGSZ;  // WcT h/l -> G h/l
    float* ZS = ws + off; off += (long)HO * M2 * D_;
    float* XS = ws + off; off += (long)H_ * B_ * D_;
    float* ZN = ws + off; off += (long)HO * M2;
    float* XN = ws + off; off += (long)H_ * B_;
    float* MJ = ws + off; off += (long)HO * M2;
    float* CV = ws + off; off += (long)HO * M2;
    float* SF2v = ws + off; off += H_;

    float* KUU2 = BIG0;
    float* T1g = BIG0;               // per-pair stride 65536, first 16384 floats
                                     // (KUU2 rows 0..63 — dead after a1a3)
    float* Linv1 = BIG2;
    float* A1 = BIG2 + MSZ;
    float* A3 = BIG2 + 2 * MSZ;
    float* Linv2 = BIG2 + 2 * MSZ;
    float* BLW = BIG2 + 3 * MSZ;
    ushort_t* LINVTh = (ushort_t*)BIG1;
    ushort_t* LINVTl = LINVTh + BIGSZ;
    ushort_t* AINVh = (ushort_t*)BIG2;
    ushort_t* AINVl = AINVh + BIGSZ;
    ushort_t* WcTh = (ushort_t*)BIG3;
    ushort_t* WcTl = WcTh + BIGSZ;
    ushort_t* Yh = (ushort_t*)BIG1;
    ushort_t* Yl = Yh + BIGSZ;
    ushort_t* Ghi = (ushort_t*)BIG3;
    ushort_t* Glo = Ghi + BIGSZ;
    ushort_t* Kg = (ushort_t*)BIG1;  // 64 MB spanning BIG1+BIG2
    const long BRoff = 128L * M2 + 128;

    // 1. preprocessing + kuu2 (fused; kuu2 split in 2 half-blocks per pair)
    k_prekuu2<<<273, 256, 0, stream>>>(theta, x, z, z_old, SF2v, XS, XN, ZS, ZN, KUU2);
    // 2. chol TL + trinv -> Linv1 ; co: WcT part A (UT, zeros, L_old)
    k_choltri_tl<<<256, 256, 0, stream>>>(KUU2, Linv1, L_old, u_tril_vec, WcTh, WcTl);
    // 3. A1 = Linv1@kuf ; A3 = Linv1@L_old
    k_a1a3<<<dim3(HO, 2), 256, 0, stream>>>(Linv1, KUU2, L_old, A1, A3);
    // 4. BLW ; Schur ; m_joint + CV zero
    k_blwschur<<<dim3(HO, 3), 256, 0, stream>>>(A1, A3, BLW, KUU2, Linv1, m_old, u_mean, MJ, CV);
    // 5. chol BR -> Linv2 ; co: T1, LINVT zeros+Linv1 part, WcT BLW part
    k_choltri_br<<<512, 256, 0, stream>>>(KUU2 + BRoff, Linv2, A1, Linv1, T1g, BLW,
                                          LINVTh, LINVTl, WcTh, WcTl);
    // 6. BLi = -Linv2 @ T1g -> LINVT BLi part (transposed planes) + Linv2 part (split x2)
    k_blicalc2<<<dim3(HO, 2), 256, 0, stream>>>(Linv2, T1g, LINVTh, LINVTl);
    // 7. AINV = LINVT (.) LINVT -> planes only + CV fused
    k_bmmx<1><<<dim3(HO, 3), 256, 0, stream>>>(LINVTh, LINVTl, LINVTh, LINVTl,
                                               nullptr, AINVh, AINVl, nullptr, nullptr,
                                               1, 1.f, MJ, CV);
    // 8. Y = AINV @ Wc -> Y planes (BIG1; LINVT dead)
    k_bmmx<0><<<dim3(HO, 4), 256, 0, stream>>>(AINVh, AINVl, WcTh, WcTl,
                                               nullptr, Yh, Yl, nullptr, nullptr,
                                               2, 1.f, nullptr, nullptr);
    // 9. G = (AINVh+AINVl) - Y Y^T -> G planes (BIG3; WcT dead)
    k_bmmx<1><<<dim3(HO, 3), 256, 0, stream>>>(Yh, Yl, Yh, Yl,
                                               nullptr, Ghi, Glo, AINVh, AINVl,
                                               0, -1.f, nullptr, nullptr);
    // 10. K build + mu (2 tiles per block; Z staged once; Kg over BIG1+BIG2)
    k_kbuild<<<dim3(8, HO), 256, 0, stream>>>(ZS, ZN, XS, XN, SF2v, CV, Kg, (float*)d_out);
    // 11. MFMA q/var
    k_kb4<<<1024, 256, 0, stream>>>(Kg, Ghi, Glo, SF2v, (float*)d_out);
}

// Round 15
// 512.953 us; speedup vs baseline: 1.0142x; 1.0142x over previous
//
#include <hip/hip_runtime.h>

#define H_ 4
#define O_ 32
#define HO 128
#define M_ 128
#define M2 256
#define D_ 16
#define B_ 1024
#define JIT 1e-4f

typedef unsigned short ushort_t;
typedef __bf16 v8bf __attribute__((ext_vector_type(8)));
typedef float v16f __attribute__((ext_vector_type(16)));
typedef unsigned short v8us __attribute__((ext_vector_type(8)));
typedef unsigned short v4us __attribute__((ext_vector_type(4)));

__device__ inline void splitbf(float v, ushort_t& hb, ushort_t& lb) {
    unsigned int u = __float_as_uint(v);
    hb = (ushort_t)(u >> 16);
    float hf = __uint_as_float((unsigned int)hb << 16);
    float r = v - hf;
    lb = (ushort_t)(__float_as_uint(r) >> 16);
}
__device__ inline float bf2f(ushort_t u) { return __uint_as_float((unsigned int)u << 16); }

__device__ __forceinline__ float rdlane(float v, int l) {
    return __int_as_float(__builtin_amdgcn_readlane(__float_as_int(v), l));
}

// aligned packed-triangle row offset: each row start rounded to 4 floats (16B)
__device__ __forceinline__ int ro_(int i) {
    int M = i >> 2, k = i & 3;
    return 4 * (M + 1) * (2 * M + k);
}

// ---------------------------------------------------------------------------
// merged preprocessing + kuu2 (kuu2 split into 2 half-blocks per pair)
// kuu2 loop in log2 domain; float4 z loads
__global__ __launch_bounds__(256) void k_prekuu2(const float* __restrict__ theta,
                                                 const float* __restrict__ x,
                                                 const float* __restrict__ z,
                                                 const float* __restrict__ z_old,
                                                 float* __restrict__ SF2,
                                                 float* __restrict__ XS, float* __restrict__ XN,
                                                 float* __restrict__ ZS, float* __restrict__ ZN,
                                                 float* __restrict__ K2) {
    int bb = blockIdx.x, t = threadIdx.x;
    __shared__ float zs[M2][D_];
    __shared__ float zn[M2];
    __shared__ float ls[D_];
    if (bb == 272) {
        if (t < H_) SF2[t] = __expf(theta[t * (D_ + 1)]);
        return;
    }
    if (bb >= 256) {
        int j = (bb - 256) * 256 + t;
        int h = j >> 10, b = j & 1023;
        if (t < D_) ls[t] = __expf(-theta[h * (D_ + 1) + 1 + t]);
        __syncthreads();
        float s = 0.f;
#pragma unroll
        for (int d = 0; d < D_; d++) {
            float v = x[b * D_ + d] * ls[d];
            XS[(long)j * D_ + d] = v;
            s += v * v;
        }
        XN[j] = s;
        return;
    }
    int pair = bb >> 1, half = bb & 1;
    int h = pair >> 5, o = pair & 31, i = t;
    if (t < D_) ls[t] = __expf(-theta[h * (D_ + 1) + 1 + t]);
    __syncthreads();
    const float* src = (i < M_) ? (z_old + ((long)o * M_ + i) * D_)
                                : (z + ((long)o * M_ + (i - M_)) * D_);
    const float4* s4 = (const float4*)src;
    float s = 0.f;
#pragma unroll
    for (int d4 = 0; d4 < 4; d4++) {
        float4 vv = s4[d4];
        vv.x *= ls[d4 * 4 + 0];
        vv.y *= ls[d4 * 4 + 1];
        vv.z *= ls[d4 * 4 + 2];
        vv.w *= ls[d4 * 4 + 3];
        *(float4*)&zs[i][d4 * 4] = vv;
        if (half == 0) *(float4*)&ZS[((long)pair * M2 + i) * D_ + d4 * 4] = vv;
        s += vv.x * vv.x + vv.y * vv.y + vv.z * vv.z + vv.w * vv.w;
    }
    zn[i] = s;
    if (half == 0) ZN[pair * M2 + i] = s;
    __syncthreads();
    const float LOG2E = 1.4426950408889634f;
    const float NHL = -0.5f * 1.4426950408889634f;
    float lsf2 = theta[h * (D_ + 1)] * LOG2E;
    float my[D_];
#pragma unroll
    for (int d = 0; d < D_; d++) my[d] = zs[i][d];
    float bx = NHL * zn[i];
    int q0 = half * 128;
    for (int q = q0; q < q0 + 128; q++) {
        float dot = 0.f;
#pragma unroll
        for (int d = 0; d < D_; d++) dot += zs[q][d] * my[d];
        float pre = fmaf(zn[q], NHL, fmaf(dot, LOG2E, bx));
        float wexp = fminf(pre, 0.f) + lsf2;
        float v;
        asm("v_exp_f32 %0, %1" : "=v"(v) : "v"(wexp));
        if (q == i) v += JIT;
        K2[(long)pair * M2 * M2 + (long)q * M2 + i] = v;
    }
}

// ---------------------------------------------------------------------------
// chol(128)+trinv body, 256 threads (spill-free), LDS ops vectorized.
// software pipeline: P3 split into P3a (next-diag tiles, tp<36) and P3b;
// wave 0 runs P1(kb+1) concurrently with waves 1-3 running P3b(kb).
#define AP_SZ 8448
#define LV_SZ 16896
#define WS_SZ 4608
#define TM_SZ 3456
#define SH_TOTAL (AP_SZ + LV_SZ + WS_SZ + TM_SZ + 128)

// wave-0 register cholesky of 32x32 diag block at column offset c0
__device__ __forceinline__ void chol_diag32(float* __restrict__ Ap, float* __restrict__ rdia,
                                            int c0, int lane, int r) {
    float a[32];
    int gr = c0 + r;
    int base = ro_(gr) + c0;
#pragma unroll
    for (int j = 0; j < 32; j++) a[j] = Ap[base + j];  // j>r: garbage, unused
#pragma unroll
    for (int k = 0; k < 32; k++) {
        float dk = rdlane(a[k], k);
        float rs = rsqrtf(dk);
        rs = rs * (1.5f - 0.5f * dk * rs * rs);  // Newton refine
        a[k] *= rs;
        if (lane == k) rdia[c0 + k] = rs;
#pragma unroll
        for (int j = k + 1; j < 32; j++) {
            float ljk = rdlane(a[k], j);
            a[j] = fmaf(-a[k], ljk, a[j]);
        }
    }
    if (lane < 32) {
#pragma unroll
        for (int j = 0; j < 32; j++)
            if (j <= r) Ap[base + j] = a[j];
    }
}

// one 4x4 trailing-syrk tile (triangular tile index tp, panel col c0)
__device__ __forceinline__ void syrk_tile(float* __restrict__ Ap, int c0, int tp) {
    int bi = (int)((sqrtf(8.f * tp + 1.f) - 1.f) * 0.5f);
    while ((bi + 1) * (bi + 2) / 2 <= tp) bi++;
    while (bi * (bi + 1) / 2 > tp) bi--;
    int bj = tp - bi * (bi + 1) / 2;
    int i0 = c0 + 32 + bi * 4, j0 = c0 + 32 + bj * 4;
    int ra[4], rb[4];
#pragma unroll
    for (int q = 0; q < 4; q++) {
        ra[q] = ro_(i0 + q) + c0;
        rb[q] = ro_(j0 + q) + c0;
    }
    float acc[4][4] = {};
#pragma unroll
    for (int k4 = 0; k4 < 8; k4++) {
        float4 av[4], bv[4];
#pragma unroll
        for (int q = 0; q < 4; q++) {
            av[q] = *(const float4*)&Ap[ra[q] + k4 * 4];
            bv[q] = *(const float4*)&Ap[rb[q] + k4 * 4];
        }
#pragma unroll
        for (int q = 0; q < 4; q++)
#pragma unroll
            for (int rr = 0; rr < 4; rr++)
                acc[q][rr] += av[q].x * bv[rr].x + av[q].y * bv[rr].y +
                              av[q].z * bv[rr].z + av[q].w * bv[rr].w;
    }
#pragma unroll
    for (int q = 0; q < 4; q++)
#pragma unroll
        for (int rr = 0; rr < 4; rr++) {
            int gi = i0 + q, gj = j0 + rr;
            if (gj <= gi) Ap[ro_(gi) + gj] -= acc[q][rr];
        }
}

__device__ __forceinline__ void choltri_body(const float* __restrict__ S, int ldsrc,
                                             float* __restrict__ Li, long b1, int t,
                                             float* __restrict__ Ap, float* __restrict__ Lv,
                                             float* __restrict__ Ws4, float* __restrict__ Tm,
                                             float* __restrict__ rdia) {
    // coalesced float4 load into aligned-row packed triangle
#pragma unroll
    for (int u = 0; u < 16; u++) {
        int idx = u * 256 + t;
        int i = idx >> 5, jc = (idx & 31) * 4;
        float4 v = *(const float4*)(S + (long)i * ldsrc + jc);
        int tb = ro_(i) + jc;
        if (jc + 3 <= i) {
            *(float4*)&Ap[tb] = v;
        } else if (jc <= i) {
            Ap[tb] = v.x;
            if (jc + 1 <= i) Ap[tb + 1] = v.y;
            if (jc + 2 <= i) Ap[tb + 2] = v.z;
        }
    }
    __syncthreads();

    int lane = t & 63;
    int wav = t >> 6;
    int r = lane & 31;

    // P1(0): diag block 0 is raw
    if (wav == 0) chol_diag32(Ap, rdia, 0, lane, r);
    __syncthreads();

    for (int kb = 0; kb < 3; kb++) {
        int c0 = kb * 32;
        int R = 96 - c0;  // 96, 64, 32
        // P2: parallel-row forward substitution (broadcast LDS reads)
        if (t < R) {
            int gi = c0 + 32 + t;
            int pb = ro_(gi) + c0;
            float xr[32];
#pragma unroll
            for (int j = 0; j < 32; j++) xr[j] = Ap[pb + j];
#pragma unroll
            for (int q = 0; q < 32; q++) {
                float xq = xr[q] * rdia[c0 + q];
                xr[q] = xq;
#pragma unroll
                for (int j = q + 1; j < 32; j++)
                    xr[j] = fmaf(-xq, Ap[ro_(c0 + j) + c0 + q], xr[j]);
            }
#pragma unroll
            for (int j = 0; j < 32; j++) Ap[pb + j] = xr[j];
        }
        __syncthreads();
        int nb = R >> 2;
        int ntile = nb * (nb + 1) / 2;
        // P3a: next-diag tiles (tp < 36 — rows/cols [c0+32, c0+64))
        if (t < 36) syrk_tile(Ap, c0, t);
        __syncthreads();
        // overlap: wave0 factors next diag while waves 1-3 finish trailing syrk.
        if (wav == 0) {
            chol_diag32(Ap, rdia, c0 + 32, lane, r);
        } else {
            for (int tp = 36 + (t - 64); tp < ntile; tp += 192) syrk_tile(Ap, c0, tp);
        }
        __syncthreads();
    }

    // parallel trinv: wave w inverts diag block w (lanes 32-63 mirror lanes 0-31)
    {
        int pb = wav;
        int c0 = pb * 32;
        float a[32];
        int gr = c0 + r;
        int base = ro_(gr) + c0;
#pragma unroll
        for (int j = 0; j < 32; j++) a[j] = Ap[base + j];
        float wr[32];
#pragma unroll
        for (int i = 0; i < 32; i++) {
            float rdi = rdia[c0 + i];
            float acc = 0.f;
#pragma unroll
            for (int j = 0; j < i; j++) {
                float lij = rdlane(a[j], i);
                acc = fmaf(lij, wr[j], acc);
            }
            wr[i] = (i == r) ? rdi : -acc * rdi;
        }
        if (lane < 32) {
            float* Wp = Ws4 + pb * 1152;
#pragma unroll
            for (int i = 0; i < 32; i++) Wp[i * 36 + r] = wr[i];
        }
    }
    __syncthreads();

    // assemble Linv in LDS (float4): diag blocks = W_i, rest 0
    for (int e = t; e < 4096; e += 256) {
        int i = e >> 5, j = (e & 31) * 4;
        int bi = i >> 5, bj = j >> 5;
        float4 v = make_float4(0.f, 0.f, 0.f, 0.f);
        if (bi == bj) v = *(const float4*)&Ws4[bi * 1152 + (i & 31) * 36 + (j & 31)];
        *(float4*)&Lv[i * 132 + j] = v;
    }
    __syncthreads();
    // block-diagonal sweep (float4): Linv[ib][b] = -W_ib * sum_k L[ib][k] Linv[k][b]
    for (int d = 1; d < 4; d++) {
        int nblk = 4 - d;
        int ne = nblk * 256;
        for (int p = t; p < ne; p += 256) {
            int b = p >> 8, rc = p & 255;
            int rr = rc >> 3, c4 = (rc & 7) * 4;
            int ib = b + d;
            int abase = ro_(ib * 32 + rr);
            float4 acc = make_float4(0.f, 0.f, 0.f, 0.f);
            for (int k = b; k < ib; k++) {
                const float* Arow = Ap + abase + k * 32;
                const float* L0 = Lv + (k * 32) * 132 + b * 32 + c4;
#pragma unroll
                for (int q4 = 0; q4 < 8; q4++) {
                    float4 ar = *(const float4*)(Arow + q4 * 4);
                    const float* Lq = L0 + (q4 * 4) * 132;
                    float4 l0 = *(const float4*)(Lq);
                    float4 l1 = *(const float4*)(Lq + 132);
                    float4 l2 = *(const float4*)(Lq + 264);
                    float4 l3 = *(const float4*)(Lq + 396);
                    acc.x += ar.x * l0.x + ar.y * l1.x + ar.z * l2.x + ar.w * l3.x;
                    acc.y += ar.x * l0.y + ar.y * l1.y + ar.z * l2.y + ar.w * l3.y;
                    acc.z += ar.x * l0.z + ar.y * l1.z + ar.z * l2.z + ar.w * l3.z;
                    acc.w += ar.x * l0.w + ar.y * l1.w + ar.z * l2.w + ar.w * l3.w;
                }
            }
            *(float4*)(Tm + b * 1152 + rr * 36 + c4) = acc;
        }
        __syncthreads();
        for (int p = t; p < ne; p += 256) {
            int b = p >> 8, rc = p & 255;
            int rr = rc >> 3, c4 = (rc & 7) * 4;
            int ib = b + d;
            const float* Wp = Ws4 + ib * 1152 + rr * 36;
            const float* T0 = Tm + b * 1152 + c4;
            float4 acc = make_float4(0.f, 0.f, 0.f, 0.f);
#pragma unroll
            for (int q4 = 0; q4 < 8; q4++) {
                float4 w4 = *(const float4*)(Wp + q4 * 4);
                const float* Tq = T0 + (q4 * 4) * 36;
                float4 t0 = *(const float4*)(Tq);
                float4 t1 = *(const float4*)(Tq + 36);
                float4 t2 = *(const float4*)(Tq + 72);
                float4 t3 = *(const float4*)(Tq + 108);
                acc.x += w4.x * t0.x + w4.y * t1.x + w4.z * t2.x + w4.w * t3.x;
                acc.y += w4.x * t0.y + w4.y * t1.y + w4.z * t2.y + w4.w * t3.y;
                acc.z += w4.x * t0.z + w4.y * t1.z + w4.z * t2.z + w4.w * t3.z;
                acc.w += w4.x * t0.w + w4.y * t1.w + w4.z * t2.w + w4.w * t3.w;
            }
            *(float4*)(Lv + (ib * 32 + rr) * 132 + b * 32 + c4) =
                make_float4(-acc.x, -acc.y, -acc.z, -acc.w);
        }
        __syncthreads();
    }
    // coalesced float4 writeback
#pragma unroll
    for (int u = 0; u < 16; u++) {
        int idx = u * 256 + t;
        int i = idx >> 5, jc = (idx & 31) * 4;
        *(float4*)(Li + b1 + (long)i * 128 + jc) = *(const float4*)(Lv + i * 132 + jc);
    }
}

// chol TL + co-scheduled WcT part A (UT BR quadrant, zeros, L_old part)
__global__ __launch_bounds__(256) void k_choltri_tl(const float* __restrict__ src,
                                                    float* __restrict__ Li,
                                                    const float* __restrict__ L_old,
                                                    const float* __restrict__ vec,
                                                    ushort_t* __restrict__ WTh,
                                                    ushort_t* __restrict__ WTl) {
    int bb = blockIdx.x, t = threadIdx.x;
    __shared__ __align__(16) float SH[SH_TOTAL];
    if (bb < 128) {
        choltri_body(src + (long)bb * ((long)M2 * M2), M2, Li, (long)bb * 16384, t,
                     SH, SH + AP_SZ, SH + AP_SZ + LV_SZ, SH + AP_SZ + LV_SZ + WS_SZ,
                     SH + AP_SZ + LV_SZ + WS_SZ + TM_SZ);
        return;
    }
    // co-path: WcT part A for pair bb-128
    int pair = bb - 128, o = pair & 31;
    long b2 = (long)pair * 65536;
    float* vs = SH;  // alias (8256 floats fits in AP region)
    float(*tile)[33] = (float(*)[33])(SH + AP_SZ);
    for (int e = t; e < M_ * (M_ + 1) / 2; e += 256) vs[e] = vec[(long)o * (M_ * (M_ + 1) / 2) + e];
    __syncthreads();
    for (int e = t; e < 16384; e += 256) {
        int n = e >> 7, k = e & 127;
        float v = (k >= n) ? vs[k * (k + 1) / 2 + n] : 0.f;
        ushort_t hb, lb;
        splitbf(v, hb, lb);
        long a = b2 + (long)(128 + n) * 256 + 128 + k;
        WTh[a] = hb;
        WTl[a] = lb;
    }
    for (int e = t; e < 16384; e += 256) {
        int n = e >> 7, k = e & 127;
        long a = b2 + (long)(128 + n) * 256 + k;
        WTh[a] = 0;
        WTl[a] = 0;
    }
    const float* sp = L_old + (long)o * 16384;
    int tx = t & 31, ty = t >> 5;
    for (int bi = 0; bi < 4; bi++)
        for (int bj = 0; bj < 4; bj++) {
            __syncthreads();
            for (int r = ty; r < 32; r += 8)
                tile[r][tx] = sp[(long)(bi * 32 + r) * 128 + bj * 32 + tx];
            __syncthreads();
            for (int r = ty; r < 32; r += 8) {
                ushort_t hb, lb;
                splitbf(tile[tx][r], hb, lb);
                long a = b2 + (long)(bj * 32 + r) * 256 + bi * 32 + tx;
                WTh[a] = hb;
                WTl[a] = lb;
            }
        }
}

// chol BR + co-scheduled: T1 = A1^T Linv1 (blocks 128-255), LINVT zeros+Linv1 part
// (256-383), WcT BLW part (384-511)
__global__ __launch_bounds__(256) void k_choltri_br(const float* __restrict__ src,
                                                    float* __restrict__ Li,
                                                    const float* __restrict__ A1,
                                                    const float* __restrict__ Linv1,
                                                    float* __restrict__ T1g,
                                                    const float* __restrict__ BLW,
                                                    ushort_t* __restrict__ LTh,
                                                    ushort_t* __restrict__ LTl,
                                                    ushort_t* __restrict__ WTh,
                                                    ushort_t* __restrict__ WTl) {
    int bb = blockIdx.x, t = threadIdx.x;
    __shared__ __align__(16) float SH[SH_TOTAL];
    if (bb < 128) {
        choltri_body(src + (long)bb * ((long)M2 * M2), M2, Li, (long)bb * 16384, t,
                     SH, SH + AP_SZ, SH + AP_SZ + LV_SZ, SH + AP_SZ + LV_SZ + WS_SZ,
                     SH + AP_SZ + LV_SZ + WS_SZ + TM_SZ);
        return;
    }
    if (bb < 256) {
        // T1 = A1^T @ Linv1 -> T1g (per-pair stride 65536)
        int pair = bb - 128;
        long b1 = (long)pair * 16384;
        float(*As)[132] = (float(*)[132])(SH + AP_SZ);
        float(*Bs)[132] = ((float(*)[132])(SH + AP_SZ)) + 16;
        const float* Apt = A1 + b1;
        const float* Bpt = Linv1 + b1;
        float* Cp = T1g + (long)pair * 65536;
        int tx = t & 15, ty = t >> 4;
        float acc[8][8] = {};
        for (int kt = 0; kt < M_; kt += 16) {
#pragma unroll
            for (int q = 0; q < 8; q++) {
                int e = q * 256 + t;
                int kk = e >> 7, m = e & 127;
                As[kk][m] = Apt[(long)(kt + kk) * 128 + m];
                Bs[kk][m] = Bpt[(long)(kt + kk) * 128 + m];
            }
            __syncthreads();
#pragma unroll
            for (int kk = 0; kk < 16; kk++) {
                float a[8], b[8];
#pragma unroll
                for (int q = 0; q < 8; q++) { a[q] = As[kk][ty + 16 * q]; b[q] = Bs[kk][tx + 16 * q]; }
#pragma unroll
                for (int q = 0; q < 8; q++)
#pragma unroll
                    for (int r = 0; r < 8; r++) acc[q][r] += a[q] * b[r];
            }
            __syncthreads();
        }
#pragma unroll
        for (int q = 0; q < 8; q++)
#pragma unroll
            for (int r = 0; r < 8; r++)
                Cp[(long)(ty + 16 * q) * 128 + tx + 16 * r] = acc[q][r];
        return;
    }
    if (bb < 384) {
        // LINVT zeros (rows 128+, cols<128) + Linv1 part
        int pair = bb - 256;
        long b2 = (long)pair * 65536, b1 = (long)pair * 16384;
        float(*tile)[33] = (float(*)[33])(SH + AP_SZ);
        for (int e = t; e < 16384; e += 256) {
            int n = e >> 7, k = e & 127;
            long a = b2 + (long)(128 + n) * 256 + k;
            LTh[a] = 0;
            LTl[a] = 0;
        }
        const float* sp = Linv1 + b1;
        int tx = t & 31, ty = t >> 5;
        for (int bi = 0; bi < 4; bi++)
            for (int bj = 0; bj < 4; bj++) {
                __syncthreads();
                for (int r = ty; r < 32; r += 8)
                    tile[r][tx] = sp[(long)(bi * 32 + r) * 128 + bj * 32 + tx];
                __syncthreads();
                for (int r = ty; r < 32; r += 8) {
                    ushort_t hb, lb;
                    splitbf(tile[tx][r], hb, lb);
                    long a = b2 + (long)(bj * 32 + r) * 256 + bi * 32 + tx;
                    LTh[a] = hb;
                    LTl[a] = lb;
                }
            }
        return;
    }
    {
        // WcT part B: BLW transposed into cols 128.. rows <128
        int pair = bb - 384;
        long b2 = (long)pair * 65536, b1 = (long)pair * 16384;
        float(*tile)[33] = (float(*)[33])(SH + AP_SZ);
        const float* sp = BLW + b1;
        int tx = t & 31, ty = t >> 5;
        for (int bi = 0; bi < 4; bi++)
            for (int bj = 0; bj < 4; bj++) {
                __syncthreads();
                for (int r = ty; r < 32; r += 8)
                    tile[r][tx] = sp[(long)(bi * 32 + r) * 128 + bj * 32 + tx];
                __syncthreads();
                for (int r = ty; r < 32; r += 8) {
                    ushort_t hb, lb;
                    splitbf(tile[tx][r], hb, lb);
                    long a = b2 + (long)(bj * 32 + r) * 256 + 128 + bi * 32 + tx;
                    WTh[a] = hb;
                    WTl[a] = lb;
                }
            }
    }
}

// merged A1/A3: y=0: A1 = Linv1 @ kuf(KUU2 TR); y=1: A3 = Linv1 @ L_old
__global__ __launch_bounds__(256) void k_a1a3(const float* __restrict__ Linv1,
                                              const float* __restrict__ KUU2,
                                              const float* __restrict__ L_old,
                                              float* __restrict__ A1, float* __restrict__ A3) {
    int pair = blockIdx.x, y = blockIdx.y, o = pair & 31;
    const float* Ap = Linv1 + (long)pair * 16384;
    const float* Bp = y ? (L_old + (long)o * 16384) : (KUU2 + (long)pair * 65536 + 128);
    int ldb = y ? 128 : 256;
    float* Cp = (y ? A3 : A1) + (long)pair * 16384;
    int t = threadIdx.x, tx = t & 15, ty = t >> 4;
    __shared__ float As[16][132], Bs[16][132];
    float acc[8][8] = {};
    for (int kt = 0; kt < M_; kt += 16) {
#pragma unroll
        for (int q = 0; q < 8; q++) {
            int e = q * 256 + t;
            int m = e >> 4, kk = e & 15;
            As[kk][m] = Ap[(long)m * 128 + kt + kk];
            int kk2 = e >> 7, n = e & 127;
            Bs[kk2][n] = Bp[(long)(kt + kk2) * ldb + n];
        }
        __syncthreads();
#pragma unroll
        for (int kk = 0; kk < 16; kk++) {
            float a[8], b[8];
#pragma unroll
            for (int q = 0; q < 8; q++) { a[q] = As[kk][ty + 16 * q]; b[q] = Bs[kk][tx + 16 * q]; }
#pragma unroll
            for (int q = 0; q < 8; q++)
#pragma unroll
                for (int r = 0; r < 8; r++) acc[q][r] += a[q] * b[r];
        }
        __syncthreads();
    }
#pragma unroll
    for (int q = 0; q < 8; q++)
#pragma unroll
        for (int r = 0; r < 8; r++)
            Cp[(long)(ty + 16 * q) * 128 + tx + 16 * r] = acc[q][r];
}

// merged: y=0: BLW = A1^T A3; y=1: KUU2_BR -= A1^T A1; y=2: m_joint + CV zero
__global__ __launch_bounds__(256) void k_blwschur(const float* __restrict__ A1,
                                                  const float* __restrict__ A3,
                                                  float* __restrict__ BLW,
                                                  float* __restrict__ KUU2,
                                                  const float* __restrict__ Linv1,
                                                  const float* __restrict__ m_old,
                                                  const float* __restrict__ u_mean,
                                                  float* __restrict__ MJ,
                                                  float* __restrict__ CV) {
    int pair = blockIdx.x, y = blockIdx.y, o = pair & 31;
    int t = threadIdx.x;
    if (y == 2) {
        CV[pair * 256 + t] = 0.f;
        __shared__ float mo[128], a2[128];
        if (t < 128) mo[t] = m_old[o * 128 + t];
        __syncthreads();
        if (t < 128) {
            const float* Lr = Linv1 + (long)pair * 16384 + (long)t * 128;
            float acc = 0.f;
            for (int j = 0; j <= t; j++) acc += Lr[j] * mo[j];
            a2[t] = acc;
        }
        __syncthreads();
        if (t < 128) {
            float m = 0.f;
            for (int i = 0; i < 128; i++) m += A1[(long)pair * 16384 + (long)i * 128 + t] * a2[i];
            MJ[pair * 256 + t] = mo[t];
            MJ[pair * 256 + 128 + t] = m + u_mean[o * 128 + t];
        }
        return;
    }
    const float* Ap = A1 + (long)pair * 16384;
    const float* Bp = (y ? A1 : A3) + (long)pair * 16384;
    float* Cp;
    int ldc;
    if (y) { Cp = KUU2 + (long)pair * 65536 + 128L * 256 + 128; ldc = 256; }
    else   { Cp = BLW + (long)pair * 16384; ldc = 128; }
    int tx = t & 15, ty = t >> 4;
    __shared__ float As[16][132], Bs[16][132];
    float acc[8][8] = {};
    for (int kt = 0; kt < M_; kt += 16) {
#pragma unroll
        for (int q = 0; q < 8; q++) {
            int e = q * 256 + t;
            int kk = e >> 7, m = e & 127;
            As[kk][m] = Ap[(long)(kt + kk) * 128 + m];
            Bs[kk][m] = Bp[(long)(kt + kk) * 128 + m];
        }
        __syncthreads();
#pragma unroll
        for (int kk = 0; kk < 16; kk++) {
            float a[8], b[8];
#pragma unroll
            for (int q = 0; q < 8; q++) { a[q] = As[kk][ty + 16 * q]; b[q] = Bs[kk][tx + 16 * q]; }
#pragma unroll
            for (int q = 0; q < 8; q++)
#pragma unroll
                for (int r = 0; r < 8; r++) acc[q][r] += a[q] * b[r];
        }
        __syncthreads();
    }
#pragma unroll
    for (int q = 0; q < 8; q++)
#pragma unroll
        for (int r = 0; r < 8; r++) {
            long idx = (long)(ty + 16 * q) * ldc + tx + 16 * r;
            if (y) Cp[idx] -= acc[q][r];
            else Cp[idx] = acc[q][r];
        }
}

// BLi = -Linv2 @ T1g; write LINVT BLi-part planes (transposed) + Linv2 part
// SPLIT over y in {0,1}: each block handles 64 output rows (full grid coverage)
__global__ __launch_bounds__(256) void k_blicalc2(const float* __restrict__ Linv2,
                                                  const float* __restrict__ T1g,
                                                  ushort_t* __restrict__ LTh,
                                                  ushort_t* __restrict__ LTl) {
    int pair = blockIdx.x, y = blockIdx.y;
    int t = threadIdx.x, tx = t & 15, ty = t >> 4;
    long b1 = (long)pair * 16384, b2 = (long)pair * 65536;
    int m0 = y * 64;
    __shared__ float T1s[64][129];
    __shared__ float As[16][68], Bs[16][132];
    const float* Apt = Linv2 + b1;
    const float* Bpt = T1g + (long)pair * 65536;
    float acc[4][8] = {};
    for (int kt = 0; kt < M_; kt += 16) {
#pragma unroll
        for (int q = 0; q < 4; q++) {
            int e = q * 256 + t;
            int m = e >> 4, kk = e & 15;  // m 0..63
            As[kk][m] = Apt[(long)(m0 + m) * 128 + kt + kk];
        }
#pragma unroll
        for (int q = 0; q < 8; q++) {
            int e = q * 256 + t;
            int kk2 = e >> 7, n = e & 127;
            Bs[kk2][n] = Bpt[(long)(kt + kk2) * 128 + n];
        }
        __syncthreads();
#pragma unroll
        for (int kk = 0; kk < 16; kk++) {
            float a[4], b[8];
#pragma unroll
            for (int q = 0; q < 4; q++) a[q] = As[kk][ty + 16 * q];
#pragma unroll
            for (int r = 0; r < 8; r++) b[r] = Bs[kk][tx + 16 * r];
#pragma unroll
            for (int q = 0; q < 4; q++)
#pragma unroll
                for (int r = 0; r < 8; r++) acc[q][r] += a[q] * b[r];
        }
        __syncthreads();
    }
#pragma unroll
    for (int q = 0; q < 4; q++)
#pragma unroll
        for (int r = 0; r < 8; r++) T1s[ty + 16 * q][tx + 16 * r] = -acc[q][r];
    __syncthreads();
    // LINVT[j][128 + m0 + i2] = BLi[m0+i2][j]
    for (int e = t; e < 8192; e += 256) {
        int j = e >> 6, i2 = e & 63;
        ushort_t hb, lb;
        splitbf(T1s[i2][j], hb, lb);
        long a = b2 + (long)j * 256 + 128 + m0 + i2;
        LTh[a] = hb;
        LTl[a] = lb;
    }
    __syncthreads();
    // load Linv2 rows [m0, m0+64) and write LINVT[128+n][128+m0+k2] = Linv2[m0+k2][n]
    for (int e = t; e < 8192; e += 256) {
        int k2 = e >> 7, j = e & 127;
        T1s[k2][j] = Apt[(long)(m0 + k2) * 128 + j];
    }
    __syncthreads();
    for (int e = t; e < 8192; e += 256) {
        int n = e >> 6, k2 = e & 63;
        ushort_t hb, lb;
        splitbf(T1s[k2][n], hb, lb);
        long a = b2 + (long)(128 + n) * 256 + 128 + m0 + k2;
        LTh[a] = hb;
        LTl[a] = lb;
    }
}

// split-bf16 MFMA batched GEMM: C = alpha*(Ah+Al)(Bh+Bl)^T [+ (DmH+DmL)]
// optional fused matvec: CVat += C @ MJv
#define BSTR 56
template <int TILES3>
__global__ __launch_bounds__(256) void k_bmmx(const ushort_t* __restrict__ Ah,
                                              const ushort_t* __restrict__ Al,
                                              const ushort_t* __restrict__ Bh,
                                              const ushort_t* __restrict__ Bl,
                                              float* __restrict__ Cf,
                                              ushort_t* __restrict__ Chi,
                                              ushort_t* __restrict__ Clo,
                                              const ushort_t* __restrict__ DmH,
                                              const ushort_t* __restrict__ DmL,
                                              int kLoMode, float alpha,
                                              const float* __restrict__ MJv,
                                              float* __restrict__ CVat) {
    int pair = blockIdx.x;
    long base = (long)pair * 65536;
    int I0, J0, mir = 0;
    if (TILES3) {
        int qb = blockIdx.y;
        I0 = (qb == 0) ? 0 : 128;
        J0 = (qb == 2) ? 0 : I0;
        mir = (qb == 2);
    } else {
        I0 = (blockIdx.y >> 1) * 128;
        J0 = (blockIdx.y & 1) * 128;
    }
    int k0 = (kLoMode == 1) ? max(I0, J0) : (kLoMode == 2) ? J0 : 0;
    int t = threadIdx.x;
    int w = t >> 6, lane = t & 63;
    int l31 = lane & 31, lhalf = lane >> 5;
    int wy = w >> 1, wx = w & 1;

    __shared__ __align__(16) ushort_t AsH[128][BSTR], AsL[128][BSTR];
    __shared__ __align__(16) ushort_t BsH[128][BSTR], BsL[128][BSTR];

    v16f acc[2][2];
#pragma unroll
    for (int mt = 0; mt < 2; mt++)
#pragma unroll
        for (int nt = 0; nt < 2; nt++)
#pragma unroll
            for (int r = 0; r < 16; r++) acc[mt][nt][r] = 0.f;

    for (int kt = k0; kt < 256; kt += 32) {
        __syncthreads();
#pragma unroll
        for (int u = 0; u < 2; u++) {
            int idx = u * 256 + t;
            int m = idx >> 2, kc = (idx & 3) * 8;
            long arow = base + (long)(I0 + m) * 256 + kt + kc;
            long brow = base + (long)(J0 + m) * 256 + kt + kc;
            *(v8us*)&AsH[m][kc] = *(const v8us*)(Ah + arow);
            *(v8us*)&AsL[m][kc] = *(const v8us*)(Al + arow);
            *(v8us*)&BsH[m][kc] = *(const v8us*)(Bh + brow);
            *(v8us*)&BsL[m][kc] = *(const v8us*)(Bl + brow);
        }
        __syncthreads();
#pragma unroll
        for (int ks = 0; ks < 2; ks++) {
            int ko = ks * 16 + lhalf * 8;
            v8bf ah[2], al[2], bh[2], bl[2];
#pragma unroll
            for (int mt = 0; mt < 2; mt++) {
                int r = wy * 64 + mt * 32 + l31;
                ah[mt] = *(const v8bf*)&AsH[r][ko];
                al[mt] = *(const v8bf*)&AsL[r][ko];
            }
#pragma unroll
            for (int nt = 0; nt < 2; nt++) {
                int r = wx * 64 + nt * 32 + l31;
                bh[nt] = *(const v8bf*)&BsH[r][ko];
                bl[nt] = *(const v8bf*)&BsL[r][ko];
            }
#pragma unroll
            for (int mt = 0; mt < 2; mt++)
#pragma unroll
                for (int nt = 0; nt < 2; nt++) {
                    acc[mt][nt] = __builtin_amdgcn_mfma_f32_32x32x16_bf16(ah[mt], bh[nt], acc[mt][nt], 0, 0, 0);
                    acc[mt][nt] = __builtin_amdgcn_mfma_f32_32x32x16_bf16(ah[mt], bl[nt], acc[mt][nt], 0, 0, 0);
                    acc[mt][nt] = __builtin_amdgcn_mfma_f32_32x32x16_bf16(al[mt], bh[nt], acc[mt][nt], 0, 0, 0);
                }
        }
    }

    float mjc[2] = {0.f, 0.f};
    float cvmir[2] = {0.f, 0.f};
    if (MJv) {
#pragma unroll
        for (int nt = 0; nt < 2; nt++)
            mjc[nt] = MJv[(long)pair * 256 + J0 + wx * 64 + nt * 32 + l31];
    }
#pragma unroll
    for (int mt = 0; mt < 2; mt++) {
#pragma unroll
        for (int r = 0; r < 16; r++) {
            int row = I0 + wy * 64 + mt * 32 + 8 * (r >> 2) + 4 * lhalf + (r & 3);
            float rowsum = 0.f;
            float mjrow = 0.f;
            if (MJv && mir) mjrow = MJv[(long)pair * 256 + row];
#pragma unroll
            for (int nt = 0; nt < 2; nt++) {
                int col = J0 + wx * 64 + nt * 32 + l31;
                long idx = base + (long)row * 256 + col;
                float v = alpha * acc[mt][nt][r];
                if (DmH) v += bf2f(DmH[idx]) + bf2f(DmL[idx]);
                ushort_t hb, lb;
                splitbf(v, hb, lb);
                if (Cf) Cf[idx] = v;
                if (Chi) { Chi[idx] = hb; Clo[idx] = lb; }
                if (mir) {
                    long idxT = base + (long)col * 256 + row;
                    if (Cf) Cf[idxT] = v;
                    if (Chi) { Chi[idxT] = hb; Clo[idxT] = lb; }
                }
                if (MJv) {
                    rowsum += v * mjc[nt];
                    if (mir) cvmir[nt] += v * mjrow;
                }
            }
            if (MJv) {
#pragma unroll
                for (int m = 1; m < 32; m <<= 1) rowsum += __shfl_xor(rowsum, m, 64);
                if (l31 == 0) atomicAdd(&CVat[(long)pair * 256 + row], rowsum);
            }
        }
    }
    if (MJv && mir) {
#pragma unroll
        for (int nt = 0; nt < 2; nt++)
            atomicAdd(&CVat[(long)pair * 256 + J0 + wx * 64 + nt * 32 + l31], cvmir[nt]);
    }
}

#define KTP 264
// K build: per (bt, pair): compute K tile (fp32 kv), write bf16 K to global, fold mu
// Z panel / zn / cv staged in LDS (broadcast ds reads replace 256 global loads/thread)
__global__ __launch_bounds__(256) void k_kbuild(const float* __restrict__ ZS, const float* __restrict__ ZN,
                                                const float* __restrict__ XS, const float* __restrict__ XN,
                                                const float* __restrict__ SF2, const float* __restrict__ CV,
                                                ushort_t* __restrict__ Kg, float* __restrict__ out) {
    int bt = blockIdx.x;
    int pair = blockIdx.y;
    int h = pair >> 5;
    int t = threadIdx.x;
    int w = t >> 6;
    int b = t & 63;

    __shared__ __align__(16) ushort_t KbT[64][KTP];
    __shared__ float mup[4][64];
    __shared__ __align__(16) float zsL[256 * 16];
    __shared__ float znv[256], cvv[256];

    const float LOG2E = 1.4426950408889634f;
    const float NHL = -0.5f * 1.4426950408889634f;
    float sf2 = SF2[h];
    float lsf2 = __log2f(sf2);

    // stage Z panel (16KB) + zn + cv
    {
        const float4* zsrc = (const float4*)(ZS + (long)pair * 256 * 16);
        float4* zdst = (float4*)zsL;
#pragma unroll
        for (int u = 0; u < 4; u++) zdst[u * 256 + t] = zsrc[u * 256 + t];
        znv[t] = ZN[pair * 256 + t];
        cvv[t] = CV[pair * 256 + t];
    }

    long bg = (long)h * B_ + bt * 64 + b;
    const float4* xrow = (const float4*)(XS + bg * 16);
    float4 x0 = xrow[0], x1 = xrow[1], x2 = xrow[2], x3 = xrow[3];
    float bx = NHL * XN[bg];
    __syncthreads();

    float mupart = 0.f;
#pragma unroll 2
    for (int j8 = 0; j8 < 8; j8++) {
        v8us kb8;
#pragma unroll
        for (int e = 0; e < 8; e++) {
            int j = w * 64 + j8 * 8 + e;
            const float4* zrow = (const float4*)(zsL + j * 16);
            float4 z0 = zrow[0], z1 = zrow[1], z2 = zrow[2], z3 = zrow[3];
            float dot = z0.x * x0.x + z0.y * x0.y + z0.z * x0.z + z0.w * x0.w +
                        z1.x * x1.x + z1.y * x1.y + z1.z * x1.z + z1.w * x1.w +
                        z2.x * x2.x + z2.y * x2.y + z2.z * x2.z + z2.w * x2.w +
                        z3.x * x3.x + z3.y * x3.y + z3.z * x3.z + z3.w * x3.w;
            float pre = fmaf(znv[j], NHL, fmaf(dot, LOG2E, bx));
            float wexp = fminf(pre, 0.f) + lsf2;
            float kv;
            asm("v_exp_f32 %0, %1" : "=v"(kv) : "v"(wexp));
            mupart += cvv[j] * kv;
            unsigned int u = __float_as_uint(kv);
            u += 0x7fffu + ((u >> 16) & 1u);
            kb8[e] = (unsigned short)(u >> 16);
        }
        *(v8us*)&KbT[b][w * 64 + j8 * 8] = kb8;
    }
    mup[w][b] = mupart;
    __syncthreads();
    long kbase = ((long)pair * 1024 + bt * 64) * 256;
#pragma unroll
    for (int e = 0; e < 8; e++) {
        int c = e * 256 + t;
        int bb = c >> 5, cj = (c & 31) * 8;
        *(v8us*)(Kg + kbase + (long)bb * 256 + cj) = *(const v8us*)&KbT[bb][cj];
    }
    if (t < 64) {
        float mu = mup[0][t] + mup[1][t] + mup[2][t] + mup[3][t];
        out[(long)pair * 1024 + bt * 64 + t] = mu;
    }
}

// MFMA q kernel, 128-wide b-tiles: 1D grid, pair = idx&127 (XCD L2 locality for G)
#define KT2 264
__global__ __launch_bounds__(256) void k_kb4(const ushort_t* __restrict__ Kg,
                                             const ushort_t* __restrict__ Ghi,
                                             const ushort_t* __restrict__ Glo,
                                             const float* __restrict__ SF2, float* __restrict__ out) {
    int pair = blockIdx.x & 127;
    int bt = blockIdx.x >> 7;
    int h = pair >> 5;
    int t = threadIdx.x;
    int w = t >> 6;
    int lane = t & 63;
    int l31 = lane & 31, lhalf = lane >> 5;

    __shared__ __align__(16) ushort_t KbT[128][KT2];
    __shared__ float qpart[4][128];

    float sf2 = SF2[h];
    long kbase = ((long)pair * 1024 + bt * 128) * 256;
#pragma unroll
    for (int e = 0; e < 16; e++) {
        int c = e * 256 + t;
        int bb = c >> 5, cj = (c & 31) * 8;
        *(v8us*)&KbT[bb][cj] = *(const v8us*)(Kg + kbase + (long)bb * 256 + cj);
    }
    __syncthreads();

    v16f acc[2][4];
#pragma unroll
    for (int mt = 0; mt < 2; mt++)
#pragma unroll
        for (int nt = 0; nt < 4; nt++)
#pragma unroll
            for (int r = 0; r < 16; r++) acc[mt][nt][r] = 0.f;

    const ushort_t* GhiP = Ghi + (long)pair * 65536;
    const ushort_t* GloP = Glo + (long)pair * 65536;
#pragma unroll 2
    for (int k0 = 0; k0 < 256; k0 += 16) {
        v8bf bfr[4];
#pragma unroll
        for (int nt = 0; nt < 4; nt++)
            bfr[nt] = *(const v8bf*)&KbT[nt * 32 + l31][k0 + lhalf * 8];
#pragma unroll
        for (int mt = 0; mt < 2; mt++) {
            int i = w * 64 + mt * 32 + l31;
            v8bf ah = *(const v8bf*)(GhiP + (long)i * 256 + k0 + lhalf * 8);
            v8bf al = *(const v8bf*)(GloP + (long)i * 256 + k0 + lhalf * 8);
#pragma unroll
            for (int nt = 0; nt < 4; nt++) {
                acc[mt][nt] = __builtin_amdgcn_mfma_f32_32x32x16_bf16(ah, bfr[nt], acc[mt][nt], 0, 0, 0);
                acc[mt][nt] = __builtin_amdgcn_mfma_f32_32x32x16_bf16(al, bfr[nt], acc[mt][nt], 0, 0, 0);
            }
        }
    }

    float qp[4] = {0.f, 0.f, 0.f, 0.f};
#pragma unroll
    for (int mt = 0; mt < 2; mt++) {
#pragma unroll
        for (int nt = 0; nt < 4; nt++) {
            int b = nt * 32 + l31;
#pragma unroll
            for (int g = 0; g < 4; g++) {
                int ibase = w * 64 + mt * 32 + 8 * g + 4 * lhalf;
                v4us k4 = *(const v4us*)&KbT[b][ibase];
#pragma unroll
                for (int e = 0; e < 4; e++) {
                    float kv = bf2f(k4[e]);
                    qp[nt] += kv * acc[mt][nt][4 * g + e];
                }
            }
        }
    }
#pragma unroll
    for (int nt = 0; nt < 4; nt++) {
        qp[nt] += __shfl_down(qp[nt], 32, 64);
        if (lhalf == 0) qpart[w][nt * 32 + l31] = qp[nt];
    }
    __syncthreads();

    if (t < 128) {
        float q = qpart[0][t] + qpart[1][t] + qpart[2][t] + qpart[3][t];
        out[(long)H_ * O_ * B_ + (long)pair * 1024 + bt * 128 + t] = sf2 - q;
    }
}

// ---------------------------------------------------------------------------
extern "C" void kernel_launch(void* const* d_in, const int* in_sizes, int n_in,
                              void* d_out, int out_size, void* d_ws, size_t ws_size,
                              hipStream_t stream) {
    const float* x = (const float*)d_in[0];
    const float* z = (const float*)d_in[1];
    const float* u_mean = (const float*)d_in[2];
    const float* u_tril_vec = (const float*)d_in[3];
    const float* m_old = (const float*)d_in[4];
    const float* L_old = (const float*)d_in[5];
    const float* z_old = (const float*)d_in[6];
    const float* theta = (const float*)d_in[7];

    const long BIGSZ = (long)HO * M2 * M2;  // 8388608
    const long MSZ = (long)HO * M_ * M_;    // 2097152

    float* ws = (float*)d_ws;
    long off = 0;
    float* BIG0 = ws + off; off += BIGSZ;  // KUU2 (+T1g in rows<64)
    float* BIG1 = ws + off; off += BIGSZ;  // LINVT h/l -> Y h/l -> Kg (part 1)
    float* BIG2 = ws + off; off += BIGSZ;  // Linv1|A1|Linv2|BLW -> AINV h/l -> Kg (part 2)
    float* BIG3 = ws + off; off += BIGSZ;  // WcT h/l -> G h/l
    float* ZS = ws + off; off += (long)HO * M2 * D_;
    float* XS = ws + off; off += (long)H_ * B_ * D_;
    float* ZN = ws + off; off += (long)HO * M2;
    float* XN = ws + off; off += (long)H_ * B_;
    float* MJ = ws + off; off += (long)HO * M2;
    float* CV = ws + off; off += (long)HO * M2;
    float* SF2v = ws + off; off += H_;

    float* KUU2 = BIG0;
    float* T1g = BIG0;               // per-pair stride 65536, first 16384 floats
                                     // (KUU2 rows 0..63 — dead after a1a3)
    float* Linv1 = BIG2;
    float* A1 = BIG2 + MSZ;
    float* A3 = BIG2 + 2 * MSZ;
    float* Linv2 = BIG2 + 2 * MSZ;
    float* BLW = BIG2 + 3 * MSZ;
    ushort_t* LINVTh = (ushort_t*)BIG1;
    ushort_t* LINVTl = LINVTh + BIGSZ;
    ushort_t* AINVh = (ushort_t*)BIG2;
    ushort_t* AINVl = AINVh + BIGSZ;
    ushort_t* WcTh = (ushort_t*)BIG3;
    ushort_t* WcTl = WcTh + BIGSZ;
    ushort_t* Yh = (ushort_t*)BIG1;
    ushort_t* Yl = Yh + BIGSZ;
    ushort_t* Ghi = (ushort_t*)BIG3;
    ushort_t* Glo = Ghi + BIGSZ;
    ushort_t* Kg = (ushort_t*)BIG1;  // 64 MB spanning BIG1+BIG2
    const long BRoff = 128L * M2 + 128;

    // 1. preprocessing + kuu2 (fused; kuu2 split in 2 half-blocks per pair)
    k_prekuu2<<<273, 256, 0, stream>>>(theta, x, z, z_old, SF2v, XS, XN, ZS, ZN, KUU2);
    // 2. chol TL + trinv -> Linv1 ; co: WcT part A (UT, zeros, L_old)
    k_choltri_tl<<<256, 256, 0, stream>>>(KUU2, Linv1, L_old, u_tril_vec, WcTh, WcTl);
    // 3. A1 = Linv1@kuf ; A3 = Linv1@L_old
    k_a1a3<<<dim3(HO, 2), 256, 0, stream>>>(Linv1, KUU2, L_old, A1, A3);
    // 4. BLW ; Schur ; m_joint + CV zero
    k_blwschur<<<dim3(HO, 3), 256, 0, stream>>>(A1, A3, BLW, KUU2, Linv1, m_old, u_mean, MJ, CV);
    // 5. chol BR -> Linv2 ; co: T1, LINVT zeros+Linv1 part, WcT BLW part
    k_choltri_br<<<512, 256, 0, stream>>>(KUU2 + BRoff, Linv2, A1, Linv1, T1g, BLW,
                                          LINVTh, LINVTl, WcTh, WcTl);
    // 6. BLi = -Linv2 @ T1g -> LINVT BLi part (transposed planes) + Linv2 part (split x2)
    k_blicalc2<<<dim3(HO, 2), 256, 0, stream>>>(Linv2, T1g, LINVTh, LINVTl);
    // 7. AINV = LINVT (.) LINVT -> planes only + CV fused
    k_bmmx<1><<<dim3(HO, 3), 256, 0, stream>>>(LINVTh, LINVTl, LINVTh, LINVTl,
                                               nullptr, AINVh, AINVl, nullptr, nullptr,
                                               1, 1.f, MJ, CV);
    // 8. Y = AINV @ Wc -> Y planes (BIG1; LINVT dead)
    k_bmmx<0><<<dim3(HO, 4), 256, 0, stream>>>(AINVh, AINVl, WcTh, WcTl,
                                               nullptr, Yh, Yl, nullptr, nullptr,
                                               2, 1.f, nullptr, nullptr);
    // 9. G = (AINVh+AINVl) - Y Y^T -> G planes (BIG3; WcT dead)
    k_bmmx<1><<<dim3(HO, 3), 256, 0, stream>>>(Yh, Yl, Yh, Yl,
                                               nullptr, Ghi, Glo, AINVh, AINVl,
                                               0, -1.f, nullptr, nullptr);
    // 10. K build + mu (Z staged once per block; Kg over BIG1+BIG2)
    k_kbuild<<<dim3(16, HO), 256, 0, stream>>>(ZS, ZN, XS, XN, SF2v, CV, Kg, (float*)d_out);
    // 11. MFMA q/var
    k_kb4<<<1024, 256, 0, stream>>>(Kg, Ghi, Glo, SF2v, (float*)d_out);
}